// Round 8
// baseline (225.957 us; speedup 1.0000x reference)
//
#include <hip/hip_runtime.h>
#include <cstdint>
#include <cstddef>

#define NTOK 4096           // B*S
#define DIM  1024           // D
#define HDIM 2048           // H
#define NE   8              // experts
#define BM   256            // GEMM row tile (experts padded to 256)
#define MAXROWS (2*NTOK + NE*BM)   // 10240 worst-case padded slots
#define MBLK (MAXROWS/BM)          // 40 m-blocks (fixed grid)

typedef __attribute__((ext_vector_type(8))) short short8;
typedef __attribute__((ext_vector_type(4))) float f32x4;
typedef __attribute__((ext_vector_type(4))) unsigned short u16x4;
typedef __attribute__((ext_vector_type(8))) unsigned short u16x8;

__device__ __forceinline__ unsigned short f2bf(float f) {
    union { float f; unsigned int u; } v; v.f = f;
    return (unsigned short)((v.u + 0x7FFFu + ((v.u >> 16) & 1u)) >> 16);
}
__device__ __forceinline__ float bf2f(unsigned short u) {
    union { unsigned int u; float f; } v; v.u = ((unsigned int)u) << 16;
    return v.f;
}

__device__ __forceinline__ void load_lds16(const void* g, void* l) {
    __builtin_amdgcn_global_load_lds(
        (const __attribute__((address_space(1))) void*)(uintptr_t)g,
        (__attribute__((address_space(3))) void*)(uintptr_t)l, 16, 0, 0);
}

// hdr layout (ints): [16..24] padded offsets (off[8]=padded_total), [32 + 16*e] cursors
// Merged: zero hdr (block 0) + gw [1024][8] f32 -> gwt [8][1024] f32
__global__ __launch_bounds__(256) void init_gwt_kernel(const float* __restrict__ gw,
                                                       float* __restrict__ gwt, int* __restrict__ hdr) {
    if (blockIdx.x == 0) hdr[threadIdx.x] = 0;
    const int i = blockIdx.x * 256 + threadIdx.x;   // 8192 total
    const int d = i >> 3, e = i & 7;
    gwt[e * DIM + d] = gw[i];
}

// Atomic-free gate: writes scores, eidx, per-token aux partial, and token-major bf16 x.
__global__ __launch_bounds__(256) void gate_kernel(
    const float* __restrict__ x, const float* __restrict__ gwt, const float* __restrict__ gb,
    float* __restrict__ scores, int* __restrict__ eidx, float* __restrict__ auxp,
    unsigned short* __restrict__ xbf)
{
    const int tid = threadIdx.x, lane = tid & 63, wv = tid >> 6;
    const int n = blockIdx.x * 4 + wv;
    float a[NE] = {0.f,0.f,0.f,0.f,0.f,0.f,0.f,0.f};
    const float* xr = x + (size_t)n * DIM;
    unsigned short* xo = xbf + (size_t)n * DIM;
    #pragma unroll
    for (int c = 0; c < 4; ++c) {
        const int d0 = c * 256 + lane * 4;
        const float4 xv = *reinterpret_cast<const float4*>(xr + d0);
        u16x4 o = { f2bf(xv.x), f2bf(xv.y), f2bf(xv.z), f2bf(xv.w) };
        *reinterpret_cast<u16x4*>(xo + d0) = o;
        #pragma unroll
        for (int e = 0; e < NE; ++e) {
            const float4 gv = *reinterpret_cast<const float4*>(gwt + e * DIM + d0);  // coalesced
            a[e] = fmaf(xv.x, gv.x, a[e]);
            a[e] = fmaf(xv.y, gv.y, a[e]);
            a[e] = fmaf(xv.z, gv.z, a[e]);
            a[e] = fmaf(xv.w, gv.w, a[e]);
        }
    }
    #pragma unroll
    for (int e = 0; e < NE; ++e)
        #pragma unroll
        for (int off = 32; off > 0; off >>= 1)
            a[e] += __shfl_xor(a[e], off);
    if (lane == 0) {
        float lg[NE], slg = 0.f, mx = -1e30f;
        #pragma unroll
        for (int e = 0; e < NE; ++e) { lg[e] = a[e] + gb[e]; slg += lg[e]; mx = fmaxf(mx, lg[e]); }
        float se = 0.f;
        #pragma unroll
        for (int e = 0; e < NE; ++e) se += expf(lg[e] - mx);
        const float lz = mx + logf(se);
        int i0 = 0;
        #pragma unroll
        for (int e = 1; e < NE; ++e) if (lg[e] > lg[i0]) i0 = e;
        int i1 = (i0 == 0) ? 1 : 0;
        #pragma unroll
        for (int e = 0; e < NE; ++e) if (e != i0 && lg[e] > lg[i1]) i1 = e;
        const float ex = expf(lg[i1] - lg[i0]);
        const float p0 = 1.f / (1.f + ex);
        scores[2*n]   = p0;
        scores[2*n+1] = ex * p0;
        eidx[2*n]   = i0;
        eidx[2*n+1] = i1;
        auxp[n] = slg - 8.f * lz;           // sum_e logp_e for this token (no atomics)
    }
}

// Single block: histogram of 8192 expert indices + 256-padded offsets. No global atomics.
__global__ __launch_bounds__(1024) void hist_offsets_kernel(const int* __restrict__ eidx, int* __restrict__ hdr)
{
    __shared__ int cnt[NE];
    const int tid = threadIdx.x, lane = tid & 63;
    if (tid < NE) cnt[tid] = 0;
    __syncthreads();
    int local[NE] = {0,0,0,0,0,0,0,0};
    #pragma unroll
    for (int j = 0; j < 8; ++j) {
        const int e = eidx[j * 1024 + tid];
        #pragma unroll
        for (int k = 0; k < NE; ++k) local[k] += (e == k);
    }
    #pragma unroll
    for (int k = 0; k < NE; ++k)
        #pragma unroll
        for (int off = 32; off > 0; off >>= 1)
            local[k] += __shfl_xor(local[k], off);
    if (lane == 0)
        #pragma unroll
        for (int k = 0; k < NE; ++k) atomicAdd(&cnt[k], local[k]);   // LDS atomics
    __syncthreads();
    if (tid == 0) {
        int off = 0;
        for (int e = 0; e < NE; ++e) {
            hdr[16 + e] = off;
            off += (cnt[e] + BM - 1) & ~(BM - 1);
        }
        hdr[16 + NE] = off;   // padded_total
    }
}

// Block-aggregated slot assignment + slot->token inverse map.
__global__ __launch_bounds__(256) void assign_kernel(
    const int* __restrict__ eidx, int* __restrict__ hdr, int* __restrict__ slot_of,
    int* __restrict__ s2t)
{
    __shared__ int cnt[NE];
    __shared__ int base[NE];
    const int tid = threadIdx.x;
    const int p = blockIdx.x * 256 + tid;
    if (tid < NE) cnt[tid] = 0;
    __syncthreads();
    const int e = eidx[p];
    const int pos = atomicAdd(&cnt[e], 1);          // LDS atomic
    __syncthreads();
    if (tid < NE) base[tid] = atomicAdd(&hdr[32 + 16 * tid], cnt[tid]);  // own cacheline
    __syncthreads();
    const int slot = hdr[16 + e] + base[e] + pos;
    slot_of[p] = slot;
    s2t[slot] = p >> 1;                             // token of this slot (pad slots: stale, clamped in gemm)
}

// in: [E][R][C] f32  ->  out: [E][C][R] bf16, 64x64 tiles, coalesced u16x8 stores.
__global__ __launch_bounds__(256) void transpose_kernel(
    const float* __restrict__ in, unsigned short* __restrict__ out, int R, int C)
{
    __shared__ unsigned short tile[64][72];   // [c][r], pad 8 shorts
    const int e = blockIdx.z;
    in  += (size_t)e * R * C;
    out += (size_t)e * R * C;
    const int c0 = blockIdx.x * 64, r0 = blockIdx.y * 64;
    const int t = threadIdx.x;
    const int lc = (t & 15) * 4, lr = t >> 4;
    #pragma unroll
    for (int p = 0; p < 4; ++p) {
        const int r = lr + p * 16;
        const float4 v = *reinterpret_cast<const float4*>(in + (size_t)(r0 + r) * C + c0 + lc);
        tile[lc+0][r] = f2bf(v.x);
        tile[lc+1][r] = f2bf(v.y);
        tile[lc+2][r] = f2bf(v.z);
        tile[lc+3][r] = f2bf(v.w);
    }
    __syncthreads();
    const int oc = t >> 2, os = (t & 3) * 16;
    const u16x8 a = *reinterpret_cast<const u16x8*>(&tile[oc][os]);
    const u16x8 b = *reinterpret_cast<const u16x8*>(&tile[oc][os + 8]);
    unsigned short* orow = out + (size_t)(c0 + oc) * R + r0 + os;
    *reinterpret_cast<u16x8*>(orow)     = a;
    *reinterpret_cast<u16x8*>(orow + 8) = b;
}

// C[row][n] = (GELU? gelu : id)(A[row][:] @ B_e[:][n]);  A:[*][KD] bf16, Bt:[E][ND][KD] bf16
// 256x256 tile, 8 waves (2Mx4N, per-wave 128x64), BK=32, 3-deep LDS pipeline,
// counted vmcnt, XOR bank swizzle (verified zero-conflict), slot->token gather on A.
template<int KD, int ND, bool GELU, bool GATHER>
__global__ __launch_bounds__(512, 2) void gemm_kernel(
    const unsigned short* __restrict__ A, const unsigned short* __restrict__ Bt,
    unsigned short* __restrict__ Cout, const int* __restrict__ hdr, const int* __restrict__ s2t)
{
    const int tid = threadIdx.x, lane = tid & 63, wv = tid >> 6;
    const int wr = wv >> 2, wc = wv & 3;          // wave grid 2M x 4N
    const int row0 = blockIdx.y * BM;
    if (row0 >= hdr[16 + NE]) return;             // beyond padded_total (uniform)
    int e = 0;
    while (e < NE - 1 && hdr[16 + e + 1] <= row0) ++e;
    const int n0 = blockIdx.x * 256;
    const unsigned short* Be = Bt + (size_t)e * KD * ND + (size_t)n0 * KD;

    // 3 buffers x (A 8192 shorts | B 8192 shorts) = 96 KB
    __shared__ __align__(16) unsigned short lds[3 * 16384];

    f32x4 acc[8][4] = {};
    const int srow = lane >> 2;                                 // row within 16-row chunk
    const int scolX = (((lane & 3) ^ ((srow >> 1) & 3)) * 8);   // swizzled source col (elements)
    const int ch0 = wv * 2, ch1 = ch0 + 1;                      // wave-uniform chunk ids (0..15)

    // per-thread global A rows (resolved once; GATHER indirects slot->token, clamped)
    int ta0 = row0 + ch0 * 16 + srow, ta1 = row0 + ch1 * 16 + srow;
    if (GATHER) {
        int t0 = s2t[ta0]; if ((unsigned)t0 >= NTOK) t0 = 0; ta0 = t0;   // pad slots: any valid row
        int t1 = s2t[ta1]; if ((unsigned)t1 >= NTOK) t1 = 0; ta1 = t1;
    }
    const size_t ga0 = (size_t)ta0 * KD, ga1 = (size_t)ta1 * KD;
    const size_t gb0 = (size_t)(ch0 * 16 + srow) * KD;
    const size_t gb1 = (size_t)(ch1 * 16 + srow) * KD;

    auto STAGE = [&](unsigned off, int k0) {   // off in shorts; 4 loads/thread
        load_lds16(A  + ga0 + k0 + scolX, &lds[off + ch0 * 512]);
        load_lds16(A  + ga1 + k0 + scolX, &lds[off + ch1 * 512]);
        load_lds16(Be + gb0 + k0 + scolX, &lds[off + 8192 + ch0 * 512]);
        load_lds16(Be + gb1 + k0 + scolX, &lds[off + 8192 + ch1 * 512]);
    };

    const int r = lane & 15;
    const int hsegX = (((lane >> 4) ^ ((r >> 1) & 3)) * 8);     // swizzled frag col (shorts)

    unsigned o0 = 0, o1 = 16384, o2 = 32768;
    STAGE(o0, 0);
    STAGE(o1, 32);
    const int NT = KD / 32;
    for (int t = 0; t < NT; ++t) {
        if (t + 2 < NT) {
            STAGE(o2, (t + 2) * 32);                              // prefetch 2 ahead
            asm volatile("s_waitcnt vmcnt(8)" ::: "memory");      // tile t landed
        } else if (t + 1 < NT) {
            asm volatile("s_waitcnt vmcnt(4)" ::: "memory");
        } else {
            asm volatile("s_waitcnt vmcnt(0)" ::: "memory");
        }
        __builtin_amdgcn_s_barrier();          // all waves' tile-t loads landed
        __builtin_amdgcn_sched_barrier(0);
        short8 af[8], bfr[4];
        #pragma unroll
        for (int mm = 0; mm < 8; ++mm)
            af[mm] = *reinterpret_cast<const short8*>(&lds[o0 + (wr*128 + mm*16 + r) * 32 + hsegX]);
        #pragma unroll
        for (int nn = 0; nn < 4; ++nn)
            bfr[nn] = *reinterpret_cast<const short8*>(&lds[o0 + 8192 + (wc*64 + nn*16 + r) * 32 + hsegX]);
        __builtin_amdgcn_s_setprio(1);
        #pragma unroll
        for (int mm = 0; mm < 8; ++mm)
            #pragma unroll
            for (int nn = 0; nn < 4; ++nn)
                acc[mm][nn] = __builtin_amdgcn_mfma_f32_16x16x32_bf16(af[mm], bfr[nn], acc[mm][nn], 0, 0, 0);
        __builtin_amdgcn_s_setprio(0);
        __builtin_amdgcn_sched_barrier(0);
        __builtin_amdgcn_s_barrier();          // reads of o0 done -> next STAGE may overwrite
        const unsigned tmp = o0; o0 = o1; o1 = o2; o2 = tmp;
    }

    const int col = lane & 15, rb = (lane >> 4) * 4;      // C/D: col=lane&15, row=(lane>>4)*4+j
    #pragma unroll
    for (int mm = 0; mm < 8; ++mm)
        #pragma unroll
        for (int nn = 0; nn < 4; ++nn)
            #pragma unroll
            for (int j = 0; j < 4; ++j) {
                const int grow = row0 + wr*128 + mm*16 + rb + j;
                const int gcol = n0 + wc*64 + nn*16 + col;
                float v = acc[mm][nn][j];
                if (GELU) v = 0.5f * v * (1.0f + erff(v * 0.70710678118654752f));
                Cout[(size_t)grow * ND + gcol] = f2bf(v);
            }
}

__global__ __launch_bounds__(256) void combine_kernel(
    const unsigned short* __restrict__ sout, const float* __restrict__ scores,
    const int* __restrict__ slot_of, float* __restrict__ out)
{
    const int n = blockIdx.x;
    const float s0 = scores[2*n], s1 = scores[2*n+1];
    const int sa = slot_of[2*n], sb = slot_of[2*n+1];
    const int d = threadIdx.x * 4;
    const u16x4 va = *reinterpret_cast<const u16x4*>(sout + (size_t)sa * DIM + d);
    const u16x4 vb = *reinterpret_cast<const u16x4*>(sout + (size_t)sb * DIM + d);
    float4 o;
    o.x = s0*bf2f(va.x) + s1*bf2f(vb.x);
    o.y = s0*bf2f(va.y) + s1*bf2f(vb.y);
    o.z = s0*bf2f(va.z) + s1*bf2f(vb.z);
    o.w = s0*bf2f(va.w) + s1*bf2f(vb.w);
    *reinterpret_cast<float4*>(out + (size_t)n * DIM + d) = o;
}

// Reduce the 4096 per-token aux partials; write aux loss scalar.
__global__ __launch_bounds__(256) void aux_kernel(const float* __restrict__ auxp, float* __restrict__ out)
{
    __shared__ float red[4];
    const int tid = threadIdx.x, lane = tid & 63, wv = tid >> 6;
    float s = 0.f;
    for (int i = tid; i < NTOK; i += 256) s += auxp[i];
    #pragma unroll
    for (int off = 32; off > 0; off >>= 1) s += __shfl_xor(s, off);
    if (lane == 0) red[wv] = s;
    __syncthreads();
    if (tid == 0) {
        const float tot = red[0] + red[1] + red[2] + red[3];
        const float t = 0.125f;
        out[(size_t)NTOK * DIM] = 0.01f * t * (logf(t) - tot / (float)(NTOK * NE));
    }
}

// ---- workspace layout (bytes) ----
constexpr size_t OFF_SCORES = 2048;
constexpr size_t OFF_IDX    = OFF_SCORES + (size_t)NTOK * 2 * 4;
constexpr size_t OFF_SLOT   = OFF_IDX    + (size_t)NTOK * 2 * 4;
constexpr size_t OFF_AUXP   = OFF_SLOT   + (size_t)NTOK * 2 * 4;
constexpr size_t OFF_S2T    = OFF_AUXP   + (size_t)NTOK * 4;
constexpr size_t OFF_GWT    = OFF_S2T    + (size_t)MAXROWS * 4;
constexpr size_t OFF_XBF    = 262144;
constexpr size_t OFF_W1T    = OFF_XBF + (size_t)NTOK * DIM * 2;
constexpr size_t OFF_W2T    = OFF_W1T + (size_t)NE * DIM * HDIM * 2;
constexpr size_t OFF_H      = OFF_W2T + (size_t)NE * DIM * HDIM * 2;
constexpr size_t OFF_SOUT   = OFF_H   + (size_t)MAXROWS * HDIM * 2;
constexpr size_t WS_NEED    = OFF_SOUT + (size_t)MAXROWS * DIM * 2;

extern "C" void kernel_launch(void* const* d_in, const int* in_sizes, int n_in,
                              void* d_out, int out_size, void* d_ws, size_t ws_size,
                              hipStream_t stream) {
    const float* x  = (const float*)d_in[0];
    const float* gw = (const float*)d_in[1];
    const float* gb = (const float*)d_in[2];
    const float* w1 = (const float*)d_in[3];
    const float* w2 = (const float*)d_in[4];
    float* out = (float*)d_out;

    if (ws_size < WS_NEED) return;   // fail loudly (output stays poisoned)

    char* ws = (char*)d_ws;
    int*   hdr     = (int*)ws;
    float* scores  = (float*)(ws + OFF_SCORES);
    int*   eidx    = (int*)(ws + OFF_IDX);
    int*   slot_of = (int*)(ws + OFF_SLOT);
    float* auxp    = (float*)(ws + OFF_AUXP);
    int*   s2t     = (int*)(ws + OFF_S2T);
    float* gwt     = (float*)(ws + OFF_GWT);
    unsigned short* xbf = (unsigned short*)(ws + OFF_XBF);
    unsigned short* w1t = (unsigned short*)(ws + OFF_W1T);
    unsigned short* w2t = (unsigned short*)(ws + OFF_W2T);
    unsigned short* h   = (unsigned short*)(ws + OFF_H);
    unsigned short* sout= (unsigned short*)(ws + OFF_SOUT);

    init_gwt_kernel<<<DIM*NE/256, 256, 0, stream>>>(gw, gwt, hdr);
    transpose_kernel<<<dim3(HDIM/64, DIM/64, NE), 256, 0, stream>>>(w1, w1t, DIM, HDIM);
    transpose_kernel<<<dim3(DIM/64, HDIM/64, NE), 256, 0, stream>>>(w2, w2t, HDIM, DIM);
    gate_kernel<<<NTOK/4, 256, 0, stream>>>(x, gwt, gb, scores, eidx, auxp, xbf);
    hist_offsets_kernel<<<1, 1024, 0, stream>>>(eidx, hdr);
    assign_kernel<<<2*NTOK/256, 256, 0, stream>>>(eidx, hdr, slot_of, s2t);
    gemm_kernel<DIM, HDIM, true,  true ><<<dim3(HDIM/256, MBLK), 512, 0, stream>>>(xbf, w1t, h, hdr, s2t);
    gemm_kernel<HDIM, DIM, false, false><<<dim3(DIM/256,  MBLK), 512, 0, stream>>>(h, w2t, sout, hdr, s2t);
    combine_kernel<<<NTOK, 256, 0, stream>>>(sout, scores, slot_of, out);
    aux_kernel<<<1, 256, 0, stream>>>(auxp, out);
}

// Round 9
// 225.598 us; speedup vs baseline: 1.0016x; 1.0016x over previous
//
#include <hip/hip_runtime.h>
#include <cstdint>
#include <cstddef>

#define NTOK 4096           // B*S
#define DIM  1024           // D
#define HDIM 2048           // H
#define NE   8              // experts
#define BMPAD 128           // expert padding / GEMM row tile
#define MAXROWS (2*NTOK + NE*BMPAD)   // 9216
#define MBLK (MAXROWS/BMPAD)          // 72 m-blocks (fixed grid)

typedef __attribute__((ext_vector_type(8))) short short8;
typedef __attribute__((ext_vector_type(4))) float f32x4;
typedef __attribute__((ext_vector_type(4))) unsigned short u16x4;
typedef __attribute__((ext_vector_type(8))) unsigned short u16x8;

__device__ __forceinline__ unsigned short f2bf(float f) {
    union { float f; unsigned int u; } v; v.f = f;
    return (unsigned short)((v.u + 0x7FFFu + ((v.u >> 16) & 1u)) >> 16);
}
__device__ __forceinline__ float bf2f(unsigned short u) {
    union { unsigned int u; float f; } v; v.u = ((unsigned int)u) << 16;
    return v.f;
}

__device__ __forceinline__ void load_lds16(const void* g, void* l) {
    __builtin_amdgcn_global_load_lds(
        (const __attribute__((address_space(1))) void*)(uintptr_t)g,
        (__attribute__((address_space(3))) void*)(uintptr_t)l, 16, 0, 0);
}

#define VM6 asm volatile("s_waitcnt vmcnt(6)" ::: "memory")
#define VM0 asm volatile("s_waitcnt vmcnt(0)" ::: "memory")

// hdr layout (ints): [16..24] padded offsets (off[8]=padded_total), [32 + 16*e] cursors
__global__ __launch_bounds__(256) void init_gwt_kernel(const float* __restrict__ gw,
                                                       float* __restrict__ gwt, int* __restrict__ hdr) {
    if (blockIdx.x == 0) hdr[threadIdx.x] = 0;
    const int i = blockIdx.x * 256 + threadIdx.x;   // 8192 total
    const int d = i >> 3, e = i & 7;
    gwt[e * DIM + d] = gw[i];
}

// Atomic-free gate: writes scores, eidx, per-token aux partial, and token-major bf16 x.
__global__ __launch_bounds__(256) void gate_kernel(
    const float* __restrict__ x, const float* __restrict__ gwt, const float* __restrict__ gb,
    float* __restrict__ scores, int* __restrict__ eidx, float* __restrict__ auxp,
    unsigned short* __restrict__ xbf)
{
    const int tid = threadIdx.x, lane = tid & 63, wv = tid >> 6;
    const int n = blockIdx.x * 4 + wv;
    float a[NE] = {0.f,0.f,0.f,0.f,0.f,0.f,0.f,0.f};
    const float* xr = x + (size_t)n * DIM;
    unsigned short* xo = xbf + (size_t)n * DIM;
    #pragma unroll
    for (int c = 0; c < 4; ++c) {
        const int d0 = c * 256 + lane * 4;
        const float4 xv = *reinterpret_cast<const float4*>(xr + d0);
        u16x4 o = { f2bf(xv.x), f2bf(xv.y), f2bf(xv.z), f2bf(xv.w) };
        *reinterpret_cast<u16x4*>(xo + d0) = o;
        #pragma unroll
        for (int e = 0; e < NE; ++e) {
            const float4 gv = *reinterpret_cast<const float4*>(gwt + e * DIM + d0);  // coalesced
            a[e] = fmaf(xv.x, gv.x, a[e]);
            a[e] = fmaf(xv.y, gv.y, a[e]);
            a[e] = fmaf(xv.z, gv.z, a[e]);
            a[e] = fmaf(xv.w, gv.w, a[e]);
        }
    }
    #pragma unroll
    for (int e = 0; e < NE; ++e)
        #pragma unroll
        for (int off = 32; off > 0; off >>= 1)
            a[e] += __shfl_xor(a[e], off);
    if (lane == 0) {
        float lg[NE], slg = 0.f, mx = -1e30f;
        #pragma unroll
        for (int e = 0; e < NE; ++e) { lg[e] = a[e] + gb[e]; slg += lg[e]; mx = fmaxf(mx, lg[e]); }
        float se = 0.f;
        #pragma unroll
        for (int e = 0; e < NE; ++e) se += expf(lg[e] - mx);
        const float lz = mx + logf(se);
        int i0 = 0;
        #pragma unroll
        for (int e = 1; e < NE; ++e) if (lg[e] > lg[i0]) i0 = e;
        int i1 = (i0 == 0) ? 1 : 0;
        #pragma unroll
        for (int e = 0; e < NE; ++e) if (e != i0 && lg[e] > lg[i1]) i1 = e;
        const float ex = expf(lg[i1] - lg[i0]);
        const float p0 = 1.f / (1.f + ex);
        scores[2*n]   = p0;
        scores[2*n+1] = ex * p0;
        eidx[2*n]   = i0;
        eidx[2*n+1] = i1;
        auxp[n] = slg - 8.f * lz;           // sum_e logp_e for this token (no atomics)
    }
}

// Single block: histogram of 8192 expert indices + 128-padded offsets. No global atomics.
__global__ __launch_bounds__(1024) void hist_offsets_kernel(const int* __restrict__ eidx, int* __restrict__ hdr)
{
    __shared__ int cnt[NE];
    const int tid = threadIdx.x, lane = tid & 63;
    if (tid < NE) cnt[tid] = 0;
    __syncthreads();
    int local[NE] = {0,0,0,0,0,0,0,0};
    #pragma unroll
    for (int j = 0; j < 8; ++j) {
        const int e = eidx[j * 1024 + tid];
        #pragma unroll
        for (int k = 0; k < NE; ++k) local[k] += (e == k);
    }
    #pragma unroll
    for (int k = 0; k < NE; ++k)
        #pragma unroll
        for (int off = 32; off > 0; off >>= 1)
            local[k] += __shfl_xor(local[k], off);
    if (lane == 0)
        #pragma unroll
        for (int k = 0; k < NE; ++k) atomicAdd(&cnt[k], local[k]);   // LDS atomics
    __syncthreads();
    if (tid == 0) {
        int off = 0;
        for (int e = 0; e < NE; ++e) {
            hdr[16 + e] = off;
            off += (cnt[e] + BMPAD - 1) & ~(BMPAD - 1);
        }
        hdr[16 + NE] = off;   // padded_total
    }
}

// Block-aggregated slot assignment + slot->token inverse map.
__global__ __launch_bounds__(256) void assign_kernel(
    const int* __restrict__ eidx, int* __restrict__ hdr, int* __restrict__ slot_of,
    int* __restrict__ s2t)
{
    __shared__ int cnt[NE];
    __shared__ int base[NE];
    const int tid = threadIdx.x;
    const int p = blockIdx.x * 256 + tid;
    if (tid < NE) cnt[tid] = 0;
    __syncthreads();
    const int e = eidx[p];
    const int pos = atomicAdd(&cnt[e], 1);          // LDS atomic
    __syncthreads();
    if (tid < NE) base[tid] = atomicAdd(&hdr[32 + 16 * tid], cnt[tid]);  // own cacheline
    __syncthreads();
    const int slot = hdr[16 + e] + base[e] + pos;
    slot_of[p] = slot;
    s2t[slot] = p >> 1;                             // token of this slot (pad slots: stale, clamped in gemm)
}

// in: [E][R][C] f32  ->  out: [E][C][R] bf16, 64x64 tiles, coalesced u16x8 stores.
__global__ __launch_bounds__(256) void transpose_kernel(
    const float* __restrict__ in, unsigned short* __restrict__ out, int R, int C)
{
    __shared__ unsigned short tile[64][72];   // [c][r], pad 8 shorts
    const int e = blockIdx.z;
    in  += (size_t)e * R * C;
    out += (size_t)e * R * C;
    const int c0 = blockIdx.x * 64, r0 = blockIdx.y * 64;
    const int t = threadIdx.x;
    const int lc = (t & 15) * 4, lr = t >> 4;
    #pragma unroll
    for (int p = 0; p < 4; ++p) {
        const int r = lr + p * 16;
        const float4 v = *reinterpret_cast<const float4*>(in + (size_t)(r0 + r) * C + c0 + lc);
        tile[lc+0][r] = f2bf(v.x);
        tile[lc+1][r] = f2bf(v.y);
        tile[lc+2][r] = f2bf(v.z);
        tile[lc+3][r] = f2bf(v.w);
    }
    __syncthreads();
    const int oc = t >> 2, os = (t & 3) * 16;
    const u16x8 a = *reinterpret_cast<const u16x8*>(&tile[oc][os]);
    const u16x8 b = *reinterpret_cast<const u16x8*>(&tile[oc][os + 8]);
    unsigned short* orow = out + (size_t)(c0 + oc) * R + r0 + os;
    *reinterpret_cast<u16x8*>(orow)     = a;
    *reinterpret_cast<u16x8*>(orow + 8) = b;
}

// C[row][n] = (GELU? gelu : id)(A[row][:] @ B_e[:][n]);  A:[*][KD] bf16, Bt:[E][ND][KD] bf16
// BM=128, BN∈{128,256}, BK=64, per-wave 64x64, 2 MFMA-phases per K-tile with
// spread staging, NBUF LDS buffers (3 -> counted vmcnt(6); 2 -> vmcnt(0)),
// XOR bank swizzle on 128-B rows, setprio around MFMA, optional slot->token gather.
template<int KD, int ND, int BN, int TH, int NBUF, bool GELU, bool GATHER>
__global__ __launch_bounds__(TH, 2) void gemm_kernel(
    const unsigned short* __restrict__ A, const unsigned short* __restrict__ Bt,
    unsigned short* __restrict__ Cout, const int* __restrict__ hdr, const int* __restrict__ s2t)
{
    constexpr int NW  = TH / 64;      // waves
    constexpr int WCN = BN / 64;      // n-waves
    constexpr int AC  = 16 / NW;      // A chunks (1 KB) per thread
    constexpr int ABUFS = 8192;       // A buffer shorts (128x64)
    constexpr int BSZ = BN * 64;      // B buffer shorts
    constexpr int NT  = KD / 64;      // K tiles

    const int tid = threadIdx.x, lane = tid & 63, wv = tid >> 6;
    const int wr = wv / WCN, wc = wv % WCN;
    const int row0 = blockIdx.y * BMPAD;
    if (row0 >= hdr[16 + NE]) return;          // beyond padded_total (uniform)
    int e = 0;
    while (e < NE - 1 && hdr[16 + e + 1] <= row0) ++e;
    const int n0 = blockIdx.x * BN;
    const unsigned short* Be = Bt + (size_t)e * KD * ND + (size_t)n0 * KD;

    __shared__ __align__(16) unsigned short lds[NBUF * (ABUFS + BSZ)];

    // ---- staging maps (pre-swizzled source col so linear LDS dest holds swizzled layout) ----
    const int lrow = lane >> 3;                       // 0..7 row within 1 KB chunk
    const int scol = ((lane & 7) ^ lrow) * 8;         // source col (shorts), XOR-swizzled

    const unsigned short* aptr[AC]; unsigned ach[AC];
    #pragma unroll
    for (int j = 0; j < AC; ++j) {
        const int ch = wv * AC + j;
        int grow = row0 + ch * 8 + lrow;
        if (GATHER) { int t0 = s2t[grow]; if ((unsigned)t0 >= NTOK) t0 = 0; grow = t0; }
        aptr[j] = A + (size_t)grow * KD + scol;
        ach[j] = ch * 512;
    }
    const unsigned short* bptr[4]; unsigned bch[4];
    #pragma unroll
    for (int j = 0; j < 4; ++j) {
        const int ch = wv * 4 + j;
        bptr[j] = Be + (size_t)(ch * 8 + lrow) * KD + scol;
        bch[j] = ch * 512;
    }

    auto STGA = [&](int tt, int bb) {
        #pragma unroll
        for (int j = 0; j < AC; ++j)
            load_lds16(aptr[j] + tt * 64, &lds[bb * ABUFS + ach[j]]);
    };
    auto STGB = [&](int tt, int bb) {
        #pragma unroll
        for (int j = 0; j < 4; ++j)
            load_lds16(bptr[j] + tt * 64, &lds[NBUF * ABUFS + bb * BSZ + bch[j]]);
    };

    // ---- fragment read maps ----
    const int r15 = lane & 15, hseg = (lane >> 4) * 8, cswz = (lane & 7) * 8;
#define LDA_(d, mm, ks) (*reinterpret_cast<const short8*>(&lds[(d)*ABUFS + (wr*64 + (mm)*16 + r15)*64 + ((((ks)*32) + hseg) ^ cswz)]))
#define LDB_(d, nn, ks) (*reinterpret_cast<const short8*>(&lds[NBUF*ABUFS + (d)*BSZ + (wc*64 + (nn)*16 + r15)*64 + ((((ks)*32) + hseg) ^ cswz)]))

    f32x4 acc[4][4] = {};
    short8 a_[2][2], b_[4][2];

    // ---- prologue: stage first NBUF-1 tiles ----
    #pragma unroll
    for (int j = 0; j < NBUF - 1; ++j) { STGA(j, j); STGB(j, j); }
    if (NBUF == 3) { VM6; } else { VM0; }
    __builtin_amdgcn_s_barrier();
    __builtin_amdgcn_sched_barrier(0);

    for (int t = 0; t < NT; ++t) {
        const int d = t % NBUF;
        const bool stage = (t + NBUF - 1) < NT;
        const int dstg = (t + NBUF - 1) % NBUF;
        // ---- phase 0: stage A(next), read A-mh0 + B-all, MFMA upper half ----
        if (stage) STGA(t + NBUF - 1, dstg);
        #pragma unroll
        for (int ks = 0; ks < 2; ++ks) {
            a_[0][ks] = LDA_(d, 0, ks);
            a_[1][ks] = LDA_(d, 1, ks);
            b_[0][ks] = LDB_(d, 0, ks);
            b_[1][ks] = LDB_(d, 1, ks);
            b_[2][ks] = LDB_(d, 2, ks);
            b_[3][ks] = LDB_(d, 3, ks);
        }
        __builtin_amdgcn_s_setprio(1);
        #pragma unroll
        for (int mm = 0; mm < 2; ++mm)
            #pragma unroll
            for (int nn = 0; nn < 4; ++nn)
                #pragma unroll
                for (int ks = 0; ks < 2; ++ks)
                    acc[mm][nn] = __builtin_amdgcn_mfma_f32_16x16x32_bf16(a_[mm][ks], b_[nn][ks], acc[mm][nn], 0, 0, 0);
        __builtin_amdgcn_s_setprio(0);
        __builtin_amdgcn_s_barrier();
        __builtin_amdgcn_sched_barrier(0);
        // ---- phase 1: stage B(next), read A-mh1, MFMA lower half ----
        if (stage) STGB(t + NBUF - 1, dstg);
        #pragma unroll
        for (int ks = 0; ks < 2; ++ks) {
            a_[0][ks] = LDA_(d, 2, ks);
            a_[1][ks] = LDA_(d, 3, ks);
        }
        __builtin_amdgcn_s_setprio(1);
        #pragma unroll
        for (int mm = 0; mm < 2; ++mm)
            #pragma unroll
            for (int nn = 0; nn < 4; ++nn)
                #pragma unroll
                for (int ks = 0; ks < 2; ++ks)
                    acc[2 + mm][nn] = __builtin_amdgcn_mfma_f32_16x16x32_bf16(a_[mm][ks], b_[nn][ks], acc[2 + mm][nn], 0, 0, 0);
        __builtin_amdgcn_s_setprio(0);
        if (NBUF == 3 && stage) { VM6; } else { VM0; }   // counted in steady state; drain at tail
        __builtin_amdgcn_s_barrier();
        __builtin_amdgcn_sched_barrier(0);
    }
#undef LDA_
#undef LDB_

    const int col = lane & 15, rb = (lane >> 4) * 4;      // C/D: col=lane&15, row=(lane>>4)*4+j
    #pragma unroll
    for (int mm = 0; mm < 4; ++mm)
        #pragma unroll
        for (int nn = 0; nn < 4; ++nn)
            #pragma unroll
            for (int j = 0; j < 4; ++j) {
                const int grow = row0 + wr*64 + mm*16 + rb + j;
                const int gcol = n0 + wc*64 + nn*16 + col;
                float v = acc[mm][nn][j];
                if (GELU) v = 0.5f * v * (1.0f + erff(v * 0.70710678118654752f));
                Cout[(size_t)grow * ND + gcol] = f2bf(v);
            }
}

__global__ __launch_bounds__(256) void combine_kernel(
    const unsigned short* __restrict__ sout, const float* __restrict__ scores,
    const int* __restrict__ slot_of, float* __restrict__ out)
{
    const int n = blockIdx.x;
    const float s0 = scores[2*n], s1 = scores[2*n+1];
    const int sa = slot_of[2*n], sb = slot_of[2*n+1];
    const int d = threadIdx.x * 4;
    const u16x4 va = *reinterpret_cast<const u16x4*>(sout + (size_t)sa * DIM + d);
    const u16x4 vb = *reinterpret_cast<const u16x4*>(sout + (size_t)sb * DIM + d);
    float4 o;
    o.x = s0*bf2f(va.x) + s1*bf2f(vb.x);
    o.y = s0*bf2f(va.y) + s1*bf2f(vb.y);
    o.z = s0*bf2f(va.z) + s1*bf2f(vb.z);
    o.w = s0*bf2f(va.w) + s1*bf2f(vb.w);
    *reinterpret_cast<float4*>(out + (size_t)n * DIM + d) = o;
}

// Reduce the 4096 per-token aux partials; write aux loss scalar.
__global__ __launch_bounds__(256) void aux_kernel(const float* __restrict__ auxp, float* __restrict__ out)
{
    __shared__ float red[4];
    const int tid = threadIdx.x, lane = tid & 63, wv = tid >> 6;
    float s = 0.f;
    for (int i = tid; i < NTOK; i += 256) s += auxp[i];
    #pragma unroll
    for (int off = 32; off > 0; off >>= 1) s += __shfl_xor(s, off);
    if (lane == 0) red[wv] = s;
    __syncthreads();
    if (tid == 0) {
        const float tot = red[0] + red[1] + red[2] + red[3];
        const float t = 0.125f;
        out[(size_t)NTOK * DIM] = 0.01f * t * (logf(t) - tot / (float)(NTOK * NE));
    }
}

// ---- workspace layout (bytes) ----
constexpr size_t OFF_SCORES = 2048;
constexpr size_t OFF_IDX    = OFF_SCORES + (size_t)NTOK * 2 * 4;
constexpr size_t OFF_SLOT   = OFF_IDX    + (size_t)NTOK * 2 * 4;
constexpr size_t OFF_AUXP   = OFF_SLOT   + (size_t)NTOK * 2 * 4;
constexpr size_t OFF_S2T    = OFF_AUXP   + (size_t)NTOK * 4;
constexpr size_t OFF_GWT    = OFF_S2T    + (size_t)MAXROWS * 4;
constexpr size_t OFF_XBF    = 262144;
constexpr size_t OFF_W1T    = OFF_XBF + (size_t)NTOK * DIM * 2;
constexpr size_t OFF_W2T    = OFF_W1T + (size_t)NE * DIM * HDIM * 2;
constexpr size_t OFF_H      = OFF_W2T + (size_t)NE * DIM * HDIM * 2;
constexpr size_t OFF_SOUT   = OFF_H   + (size_t)MAXROWS * HDIM * 2;
constexpr size_t WS_NEED    = OFF_SOUT + (size_t)MAXROWS * DIM * 2;

extern "C" void kernel_launch(void* const* d_in, const int* in_sizes, int n_in,
                              void* d_out, int out_size, void* d_ws, size_t ws_size,
                              hipStream_t stream) {
    const float* x  = (const float*)d_in[0];
    const float* gw = (const float*)d_in[1];
    const float* gb = (const float*)d_in[2];
    const float* w1 = (const float*)d_in[3];
    const float* w2 = (const float*)d_in[4];
    float* out = (float*)d_out;

    if (ws_size < WS_NEED) return;   // fail loudly (output stays poisoned)

    char* ws = (char*)d_ws;
    int*   hdr     = (int*)ws;
    float* scores  = (float*)(ws + OFF_SCORES);
    int*   eidx    = (int*)(ws + OFF_IDX);
    int*   slot_of = (int*)(ws + OFF_SLOT);
    float* auxp    = (float*)(ws + OFF_AUXP);
    int*   s2t     = (int*)(ws + OFF_S2T);
    float* gwt     = (float*)(ws + OFF_GWT);
    unsigned short* xbf = (unsigned short*)(ws + OFF_XBF);
    unsigned short* w1t = (unsigned short*)(ws + OFF_W1T);
    unsigned short* w2t = (unsigned short*)(ws + OFF_W2T);
    unsigned short* h   = (unsigned short*)(ws + OFF_H);
    unsigned short* sout= (unsigned short*)(ws + OFF_SOUT);

    init_gwt_kernel<<<DIM*NE/256, 256, 0, stream>>>(gw, gwt, hdr);
    transpose_kernel<<<dim3(HDIM/64, DIM/64, NE), 256, 0, stream>>>(w1, w1t, DIM, HDIM);
    transpose_kernel<<<dim3(DIM/64, HDIM/64, NE), 256, 0, stream>>>(w2, w2t, HDIM, DIM);
    gate_kernel<<<NTOK/4, 256, 0, stream>>>(x, gwt, gb, scores, eidx, auxp, xbf);
    hist_offsets_kernel<<<1, 1024, 0, stream>>>(eidx, hdr);
    assign_kernel<<<2*NTOK/256, 256, 0, stream>>>(eidx, hdr, slot_of, s2t);
    // GEMM1: 128x256 tile, 8 waves, 3 LDS buffers (144 KB), counted vmcnt(6)
    gemm_kernel<DIM, HDIM, 256, 512, 3, true,  true ><<<dim3(HDIM/256, MBLK), 512, 0, stream>>>(xbf, w1t, h, hdr, s2t);
    // GEMM2: 128x128 tile, 4 waves, 2 LDS buffers (64 KB -> 2 blocks/CU)
    gemm_kernel<HDIM, DIM, 128, 256, 2, false, false><<<dim3(DIM/128, MBLK), 256, 0, stream>>>(h, w2t, sout, hdr, s2t);
    combine_kernel<<<NTOK, 256, 0, stream>>>(sout, scores, slot_of, out);
    aux_kernel<<<1, 256, 0, stream>>>(auxp, out);
}

// Round 10
// 214.734 us; speedup vs baseline: 1.0523x; 1.0506x over previous
//
#include <hip/hip_runtime.h>
#include <cstdint>
#include <cstddef>

#define NTOK 4096           // B*S
#define DIM  1024           // D
#define HDIM 2048           // H
#define NE   8              // experts
#define BM   128            // GEMM row tile / expert padding
#define MAXROWS (2*NTOK + NE*BM)   // 9216 worst-case padded slots
#define MBLK (MAXROWS/BM)          // 72 m-blocks (fixed grid)

typedef __attribute__((ext_vector_type(8))) short short8;
typedef __attribute__((ext_vector_type(4))) float f32x4;
typedef __attribute__((ext_vector_type(4))) unsigned short u16x4;
typedef __attribute__((ext_vector_type(8))) unsigned short u16x8;

__device__ __forceinline__ unsigned short f2bf(float f) {
    union { float f; unsigned int u; } v; v.f = f;
    return (unsigned short)((v.u + 0x7FFFu + ((v.u >> 16) & 1u)) >> 16);
}
__device__ __forceinline__ float bf2f(unsigned short u) {
    union { unsigned int u; float f; } v; v.u = ((unsigned int)u) << 16;
    return v.f;
}

__device__ __forceinline__ void load_lds16(const void* g, void* l) {
    __builtin_amdgcn_global_load_lds(
        (const __attribute__((address_space(1))) void*)(uintptr_t)g,
        (__attribute__((address_space(3))) void*)(uintptr_t)l, 16, 0, 0);
}

// hdr layout (ints): [16..24] padded offsets (off[8]=padded_total), [32 + 16*e] cursors
__global__ __launch_bounds__(256) void init_gwt_kernel(const float* __restrict__ gw,
                                                       float* __restrict__ gwt, int* __restrict__ hdr) {
    if (blockIdx.x == 0) hdr[threadIdx.x] = 0;
    const int i = blockIdx.x * 256 + threadIdx.x;   // 8192 total
    const int d = i >> 3, e = i & 7;
    gwt[e * DIM + d] = gw[i];
}

// Atomic-free gate: writes scores, eidx, per-token aux partial, and token-major bf16 x.
__global__ __launch_bounds__(256) void gate_kernel(
    const float* __restrict__ x, const float* __restrict__ gwt, const float* __restrict__ gb,
    float* __restrict__ scores, int* __restrict__ eidx, float* __restrict__ auxp,
    unsigned short* __restrict__ xbf)
{
    const int tid = threadIdx.x, lane = tid & 63, wv = tid >> 6;
    const int n = blockIdx.x * 4 + wv;
    float a[NE] = {0.f,0.f,0.f,0.f,0.f,0.f,0.f,0.f};
    const float* xr = x + (size_t)n * DIM;
    unsigned short* xo = xbf + (size_t)n * DIM;
    #pragma unroll
    for (int c = 0; c < 4; ++c) {
        const int d0 = c * 256 + lane * 4;
        const float4 xv = *reinterpret_cast<const float4*>(xr + d0);
        u16x4 o = { f2bf(xv.x), f2bf(xv.y), f2bf(xv.z), f2bf(xv.w) };
        *reinterpret_cast<u16x4*>(xo + d0) = o;
        #pragma unroll
        for (int e = 0; e < NE; ++e) {
            const float4 gv = *reinterpret_cast<const float4*>(gwt + e * DIM + d0);  // coalesced
            a[e] = fmaf(xv.x, gv.x, a[e]);
            a[e] = fmaf(xv.y, gv.y, a[e]);
            a[e] = fmaf(xv.z, gv.z, a[e]);
            a[e] = fmaf(xv.w, gv.w, a[e]);
        }
    }
    #pragma unroll
    for (int e = 0; e < NE; ++e)
        #pragma unroll
        for (int off = 32; off > 0; off >>= 1)
            a[e] += __shfl_xor(a[e], off);
    if (lane == 0) {
        float lg[NE], slg = 0.f, mx = -1e30f;
        #pragma unroll
        for (int e = 0; e < NE; ++e) { lg[e] = a[e] + gb[e]; slg += lg[e]; mx = fmaxf(mx, lg[e]); }
        float se = 0.f;
        #pragma unroll
        for (int e = 0; e < NE; ++e) se += expf(lg[e] - mx);
        const float lz = mx + logf(se);
        int i0 = 0;
        #pragma unroll
        for (int e = 1; e < NE; ++e) if (lg[e] > lg[i0]) i0 = e;
        int i1 = (i0 == 0) ? 1 : 0;
        #pragma unroll
        for (int e = 0; e < NE; ++e) if (e != i0 && lg[e] > lg[i1]) i1 = e;
        const float ex = expf(lg[i1] - lg[i0]);
        const float p0 = 1.f / (1.f + ex);
        scores[2*n]   = p0;
        scores[2*n+1] = ex * p0;
        eidx[2*n]   = i0;
        eidx[2*n+1] = i1;
        auxp[n] = slg - 8.f * lz;           // sum_e logp_e for this token (no atomics)
    }
}

// Single block: histogram of 8192 expert indices + 128-padded offsets. No global atomics.
__global__ __launch_bounds__(1024) void hist_offsets_kernel(const int* __restrict__ eidx, int* __restrict__ hdr)
{
    __shared__ int cnt[NE];
    const int tid = threadIdx.x, lane = tid & 63;
    if (tid < NE) cnt[tid] = 0;
    __syncthreads();
    int local[NE] = {0,0,0,0,0,0,0,0};
    #pragma unroll
    for (int j = 0; j < 8; ++j) {
        const int e = eidx[j * 1024 + tid];
        #pragma unroll
        for (int k = 0; k < NE; ++k) local[k] += (e == k);
    }
    #pragma unroll
    for (int k = 0; k < NE; ++k)
        #pragma unroll
        for (int off = 32; off > 0; off >>= 1)
            local[k] += __shfl_xor(local[k], off);
    if (lane == 0)
        #pragma unroll
        for (int k = 0; k < NE; ++k) atomicAdd(&cnt[k], local[k]);   // LDS atomics
    __syncthreads();
    if (tid == 0) {
        int off = 0;
        for (int e = 0; e < NE; ++e) {
            hdr[16 + e] = off;
            off += (cnt[e] + BM - 1) & ~(BM - 1);
        }
        hdr[16 + NE] = off;   // padded_total
    }
}

// Block-aggregated slot assignment + slot->token inverse map.
__global__ __launch_bounds__(256) void assign_kernel(
    const int* __restrict__ eidx, int* __restrict__ hdr, int* __restrict__ slot_of,
    int* __restrict__ s2t)
{
    __shared__ int cnt[NE];
    __shared__ int base[NE];
    const int tid = threadIdx.x;
    const int p = blockIdx.x * 256 + tid;
    if (tid < NE) cnt[tid] = 0;
    __syncthreads();
    const int e = eidx[p];
    const int pos = atomicAdd(&cnt[e], 1);          // LDS atomic
    __syncthreads();
    if (tid < NE) base[tid] = atomicAdd(&hdr[32 + 16 * tid], cnt[tid]);  // own cacheline
    __syncthreads();
    const int slot = hdr[16 + e] + base[e] + pos;
    slot_of[p] = slot;
    s2t[slot] = p >> 1;                             // token of this slot (pad slots: stale, clamped in gemm)
}

// in: [E][R][C] f32  ->  out: [E][C][R] bf16, 64x64 tiles, coalesced u16x8 stores.
__global__ __launch_bounds__(256) void transpose_kernel(
    const float* __restrict__ in, unsigned short* __restrict__ out, int R, int C)
{
    __shared__ unsigned short tile[64][72];   // [c][r], pad 8 shorts
    const int e = blockIdx.z;
    in  += (size_t)e * R * C;
    out += (size_t)e * R * C;
    const int c0 = blockIdx.x * 64, r0 = blockIdx.y * 64;
    const int t = threadIdx.x;
    const int lc = (t & 15) * 4, lr = t >> 4;
    #pragma unroll
    for (int p = 0; p < 4; ++p) {
        const int r = lr + p * 16;
        const float4 v = *reinterpret_cast<const float4*>(in + (size_t)(r0 + r) * C + c0 + lc);
        tile[lc+0][r] = f2bf(v.x);
        tile[lc+1][r] = f2bf(v.y);
        tile[lc+2][r] = f2bf(v.z);
        tile[lc+3][r] = f2bf(v.w);
    }
    __syncthreads();
    const int oc = t >> 2, os = (t & 3) * 16;
    const u16x8 a = *reinterpret_cast<const u16x8*>(&tile[oc][os]);
    const u16x8 b = *reinterpret_cast<const u16x8*>(&tile[oc][os + 8]);
    unsigned short* orow = out + (size_t)(c0 + oc) * R + r0 + os;
    *reinterpret_cast<u16x8*>(orow)     = a;
    *reinterpret_cast<u16x8*>(orow + 8) = b;
}

// C[row][n] = (GELU? gelu : id)(A[row][:] @ B_e[:][n]);  A:[*][KD] bf16, Bt:[E][ND][KD] bf16
// R6-proven skeleton, widened: 128x256 tile, 4 waves (per-wave 64x128), BK=32,
// 3-deep LDS pipeline (72 KB -> 2 blocks/CU), counted vmcnt(12/6/0),
// XOR bank swizzle (R6-verified zero-conflict maps), slot->token gather on A.
template<int KD, bool GELU, bool GATHER>
__global__ __launch_bounds__(256, 2) void gemm_kernel(
    const unsigned short* __restrict__ A, const unsigned short* __restrict__ Bt, int ND,
    unsigned short* __restrict__ Cout, const int* __restrict__ hdr, const int* __restrict__ s2t)
{
    const int tid = threadIdx.x, lane = tid & 63, wv = tid >> 6;
    const int wr = wv >> 1, wc = wv & 1;          // wave grid 2M x 2N, per-wave 64x128
    const int row0 = blockIdx.y * BM;
    if (row0 >= hdr[16 + NE]) return;             // beyond padded_total (uniform)
    int e = 0;
    while (e < NE - 1 && hdr[16 + e + 1] <= row0) ++e;
    const int n0 = blockIdx.x * 256;
    const unsigned short* Be = Bt + (size_t)e * KD * ND + (size_t)n0 * KD;

    // 3 buffers x (A 4096 shorts | B 8192 shorts) = 72 KB
    __shared__ __align__(16) unsigned short lds[3 * 12288];

    f32x4 acc[4][8] = {};
    const int srow = lane >> 2, scolX = (((lane & 3) ^ ((lane >> 3) & 3)) * 8);  // R6 staging map
    const int ch0 = wv * 2, ch1 = ch0 + 1;                                       // A chunks (8 x 1KB)

    // per-thread global A rows (resolved once; GATHER indirects slot->token, clamped)
    int ta0 = row0 + ch0 * 16 + srow, ta1 = row0 + ch1 * 16 + srow;
    if (GATHER) {
        int t0 = s2t[ta0]; if ((unsigned)t0 >= NTOK) t0 = 0; ta0 = t0;
        int t1 = s2t[ta1]; if ((unsigned)t1 >= NTOK) t1 = 0; ta1 = t1;
    }
    const size_t ga0 = (size_t)ta0 * KD, ga1 = (size_t)ta1 * KD;
    // B: 16 chunks, 4 per wave
    size_t gb[4];
    #pragma unroll
    for (int j = 0; j < 4; ++j) gb[j] = (size_t)((wv * 4 + j) * 16 + srow) * KD;

    auto STAGE = [&](unsigned off, int k0) {   // off in shorts; 6 loads/thread
        load_lds16(A + ga0 + k0 + scolX, &lds[off + ch0 * 512]);
        load_lds16(A + ga1 + k0 + scolX, &lds[off + ch1 * 512]);
        #pragma unroll
        for (int j = 0; j < 4; ++j)
            load_lds16(Be + gb[j] + k0 + scolX, &lds[off + 4096 + (wv * 4 + j) * 512]);
    };

    const int r = lane & 15;
    const int hsegX = (((lane >> 4) ^ ((r >> 1) & 3)) * 8);     // R6 frag-read map

    unsigned o0 = 0, o1 = 12288, o2 = 24576;
    STAGE(o0, 0);
    STAGE(o1, 32);
    const int NT = KD / 32;
    for (int t = 0; t < NT; ++t) {
        if (t + 2 < NT) {
            STAGE(o2, (t + 2) * 32);                              // prefetch 2 ahead
            asm volatile("s_waitcnt vmcnt(12)" ::: "memory");     // tile t landed
        } else if (t + 1 < NT) {
            asm volatile("s_waitcnt vmcnt(6)" ::: "memory");
        } else {
            asm volatile("s_waitcnt vmcnt(0)" ::: "memory");
        }
        __builtin_amdgcn_s_barrier();          // all waves' tile-t loads landed
        __builtin_amdgcn_sched_barrier(0);
        short8 af[4], bfr[8];
        #pragma unroll
        for (int mm = 0; mm < 4; ++mm)
            af[mm] = *reinterpret_cast<const short8*>(&lds[o0 + (wr*64 + mm*16 + r) * 32 + hsegX]);
        #pragma unroll
        for (int nn = 0; nn < 8; ++nn)
            bfr[nn] = *reinterpret_cast<const short8*>(&lds[o0 + 4096 + (wc*128 + nn*16 + r) * 32 + hsegX]);
        __builtin_amdgcn_s_setprio(1);
        #pragma unroll
        for (int mm = 0; mm < 4; ++mm)
            #pragma unroll
            for (int nn = 0; nn < 8; ++nn)
                acc[mm][nn] = __builtin_amdgcn_mfma_f32_16x16x32_bf16(af[mm], bfr[nn], acc[mm][nn], 0, 0, 0);
        __builtin_amdgcn_s_setprio(0);
        __builtin_amdgcn_sched_barrier(0);
        __builtin_amdgcn_s_barrier();          // reads of o0 done -> next STAGE may overwrite
        const unsigned tmp = o0; o0 = o1; o1 = o2; o2 = tmp;
    }

    const int col = lane & 15, rb = (lane >> 4) * 4;      // C/D: col=lane&15, row=(lane>>4)*4+j
    #pragma unroll
    for (int mm = 0; mm < 4; ++mm)
        #pragma unroll
        for (int nn = 0; nn < 8; ++nn)
            #pragma unroll
            for (int j = 0; j < 4; ++j) {
                const int grow = row0 + wr*64 + mm*16 + rb + j;
                const int gcol = n0 + wc*128 + nn*16 + col;
                float v = acc[mm][nn][j];
                if (GELU) v = 0.5f * v * (1.0f + erff(v * 0.70710678118654752f));
                Cout[(size_t)grow * ND + gcol] = f2bf(v);
            }
}

__global__ __launch_bounds__(256) void combine_kernel(
    const unsigned short* __restrict__ sout, const float* __restrict__ scores,
    const int* __restrict__ slot_of, float* __restrict__ out)
{
    const int n = blockIdx.x;
    const float s0 = scores[2*n], s1 = scores[2*n+1];
    const int sa = slot_of[2*n], sb = slot_of[2*n+1];
    const int d = threadIdx.x * 4;
    const u16x4 va = *reinterpret_cast<const u16x4*>(sout + (size_t)sa * DIM + d);
    const u16x4 vb = *reinterpret_cast<const u16x4*>(sout + (size_t)sb * DIM + d);
    float4 o;
    o.x = s0*bf2f(va.x) + s1*bf2f(vb.x);
    o.y = s0*bf2f(va.y) + s1*bf2f(vb.y);
    o.z = s0*bf2f(va.z) + s1*bf2f(vb.z);
    o.w = s0*bf2f(va.w) + s1*bf2f(vb.w);
    *reinterpret_cast<float4*>(out + (size_t)n * DIM + d) = o;
}

// Reduce the 4096 per-token aux partials; write aux loss scalar.
__global__ __launch_bounds__(256) void aux_kernel(const float* __restrict__ auxp, float* __restrict__ out)
{
    __shared__ float red[4];
    const int tid = threadIdx.x, lane = tid & 63, wv = tid >> 6;
    float s = 0.f;
    for (int i = tid; i < NTOK; i += 256) s += auxp[i];
    #pragma unroll
    for (int off = 32; off > 0; off >>= 1) s += __shfl_xor(s, off);
    if (lane == 0) red[wv] = s;
    __syncthreads();
    if (tid == 0) {
        const float tot = red[0] + red[1] + red[2] + red[3];
        const float t = 0.125f;
        out[(size_t)NTOK * DIM] = 0.01f * t * (logf(t) - tot / (float)(NTOK * NE));
    }
}

// ---- workspace layout (bytes) ----
constexpr size_t OFF_SCORES = 2048;
constexpr size_t OFF_IDX    = OFF_SCORES + (size_t)NTOK * 2 * 4;
constexpr size_t OFF_SLOT   = OFF_IDX    + (size_t)NTOK * 2 * 4;
constexpr size_t OFF_AUXP   = OFF_SLOT   + (size_t)NTOK * 2 * 4;
constexpr size_t OFF_S2T    = OFF_AUXP   + (size_t)NTOK * 4;
constexpr size_t OFF_GWT    = OFF_S2T    + (size_t)MAXROWS * 4;
constexpr size_t OFF_XBF    = 262144;
constexpr size_t OFF_W1T    = OFF_XBF + (size_t)NTOK * DIM * 2;
constexpr size_t OFF_W2T    = OFF_W1T + (size_t)NE * DIM * HDIM * 2;
constexpr size_t OFF_H      = OFF_W2T + (size_t)NE * DIM * HDIM * 2;
constexpr size_t OFF_SOUT   = OFF_H   + (size_t)MAXROWS * HDIM * 2;
constexpr size_t WS_NEED    = OFF_SOUT + (size_t)MAXROWS * DIM * 2;

extern "C" void kernel_launch(void* const* d_in, const int* in_sizes, int n_in,
                              void* d_out, int out_size, void* d_ws, size_t ws_size,
                              hipStream_t stream) {
    const float* x  = (const float*)d_in[0];
    const float* gw = (const float*)d_in[1];
    const float* gb = (const float*)d_in[2];
    const float* w1 = (const float*)d_in[3];
    const float* w2 = (const float*)d_in[4];
    float* out = (float*)d_out;

    if (ws_size < WS_NEED) return;   // fail loudly (output stays poisoned)

    char* ws = (char*)d_ws;
    int*   hdr     = (int*)ws;
    float* scores  = (float*)(ws + OFF_SCORES);
    int*   eidx    = (int*)(ws + OFF_IDX);
    int*   slot_of = (int*)(ws + OFF_SLOT);
    float* auxp    = (float*)(ws + OFF_AUXP);
    int*   s2t     = (int*)(ws + OFF_S2T);
    float* gwt     = (float*)(ws + OFF_GWT);
    unsigned short* xbf = (unsigned short*)(ws + OFF_XBF);
    unsigned short* w1t = (unsigned short*)(ws + OFF_W1T);
    unsigned short* w2t = (unsigned short*)(ws + OFF_W2T);
    unsigned short* h   = (unsigned short*)(ws + OFF_H);
    unsigned short* sout= (unsigned short*)(ws + OFF_SOUT);

    init_gwt_kernel<<<DIM*NE/256, 256, 0, stream>>>(gw, gwt, hdr);
    transpose_kernel<<<dim3(HDIM/64, DIM/64, NE), 256, 0, stream>>>(w1, w1t, DIM, HDIM);
    transpose_kernel<<<dim3(DIM/64, HDIM/64, NE), 256, 0, stream>>>(w2, w2t, HDIM, DIM);
    gate_kernel<<<NTOK/4, 256, 0, stream>>>(x, gwt, gb, scores, eidx, auxp, xbf);
    hist_offsets_kernel<<<1, 1024, 0, stream>>>(eidx, hdr);
    assign_kernel<<<2*NTOK/256, 256, 0, stream>>>(eidx, hdr, slot_of, s2t);
    gemm_kernel<DIM,  true,  true ><<<dim3(HDIM/256, MBLK), 256, 0, stream>>>(xbf, w1t, HDIM, h, hdr, s2t);
    gemm_kernel<HDIM, false, false><<<dim3(DIM/256,  MBLK), 256, 0, stream>>>(h, w2t, DIM, sout, hdr, s2t);
    combine_kernel<<<NTOK, 256, 0, stream>>>(sout, scores, slot_of, out);
    aux_kernel<<<1, 256, 0, stream>>>(auxp, out);
}

// Round 11
// 198.766 us; speedup vs baseline: 1.1368x; 1.0803x over previous
//
#include <hip/hip_runtime.h>
#include <cstdint>
#include <cstddef>

#define NTOK 4096           // B*S
#define DIM  1024           // D
#define HDIM 2048           // H
#define NE   8              // experts
#define BM   128            // GEMM row tile / expert padding
#define MAXROWS (2*NTOK + NE*BM)   // 9216 worst-case padded slots
#define MBLK (MAXROWS/BM)          // 72 m-blocks (fixed grid)

typedef __attribute__((ext_vector_type(8))) short short8;
typedef __attribute__((ext_vector_type(4))) float f32x4;
typedef __attribute__((ext_vector_type(4))) unsigned short u16x4;
typedef __attribute__((ext_vector_type(8))) unsigned short u16x8;

__device__ __forceinline__ unsigned short f2bf(float f) {
    union { float f; unsigned int u; } v; v.f = f;
    return (unsigned short)((v.u + 0x7FFFu + ((v.u >> 16) & 1u)) >> 16);
}
__device__ __forceinline__ float bf2f(unsigned short u) {
    union { unsigned int u; float f; } v; v.u = ((unsigned int)u) << 16;
    return v.f;
}

__device__ __forceinline__ void load_lds16(const void* g, void* l) {
    __builtin_amdgcn_global_load_lds(
        (const __attribute__((address_space(1))) void*)(uintptr_t)g,
        (__attribute__((address_space(3))) void*)(uintptr_t)l, 16, 0, 0);
}

// ---- prep kernel: fused w1-transpose | w2-transpose | gate | hdr-zero ----
// blocks [0,4096): w1 [E][1024][2048] f32 -> w1t [E][2048][1024] bf16
// blocks [4096,8192): w2 [E][2048][1024] f32 -> w2t [E][1024][2048] bf16
// blocks [8192,9216): gate, 4 tokens/block (reads gw directly)
// block 9216: zero hdr
__device__ __forceinline__ void transpose_tile(
    const float* __restrict__ in, unsigned short* __restrict__ out,
    int R, int C, int bx, int by, int e, unsigned short (*tile)[72])
{
    in  += (size_t)e * R * C;
    out += (size_t)e * R * C;
    const int c0 = bx * 64, r0 = by * 64;
    const int t = threadIdx.x;
    const int lc = (t & 15) * 4, lr = t >> 4;
    #pragma unroll
    for (int p = 0; p < 4; ++p) {
        const int r = lr + p * 16;
        const float4 v = *reinterpret_cast<const float4*>(in + (size_t)(r0 + r) * C + c0 + lc);
        tile[lc+0][r] = f2bf(v.x);
        tile[lc+1][r] = f2bf(v.y);
        tile[lc+2][r] = f2bf(v.z);
        tile[lc+3][r] = f2bf(v.w);
    }
    __syncthreads();
    const int oc = t >> 2, os = (t & 3) * 16;
    const u16x8 a = *reinterpret_cast<const u16x8*>(&tile[oc][os]);
    const u16x8 b = *reinterpret_cast<const u16x8*>(&tile[oc][os + 8]);
    unsigned short* orow = out + (size_t)(c0 + oc) * R + r0 + os;
    *reinterpret_cast<u16x8*>(orow)     = a;
    *reinterpret_cast<u16x8*>(orow + 8) = b;
}

__global__ __launch_bounds__(256) void prep_kernel(
    const float* __restrict__ x,  const float* __restrict__ gw, const float* __restrict__ gb,
    const float* __restrict__ w1, const float* __restrict__ w2,
    unsigned short* __restrict__ w1t, unsigned short* __restrict__ w2t,
    float* __restrict__ scores, int* __restrict__ eidx, float* __restrict__ auxp,
    unsigned short* __restrict__ xbf, int* __restrict__ hdr)
{
    __shared__ unsigned short tile[64][72];   // transposes only
    const int id = blockIdx.x;
    if (id < 4096) {                           // w1: R=1024 C=2048, 32x16 tiles/expert
        const int e = id >> 9, rem = id & 511;
        transpose_tile(w1, w1t, DIM, HDIM, rem & 31, rem >> 5, e, tile);
        return;
    }
    if (id < 8192) {                           // w2: R=2048 C=1024, 16x32 tiles/expert
        const int j = id - 4096;
        const int e = j >> 9, rem = j & 511;
        transpose_tile(w2, w2t, HDIM, DIM, rem & 15, rem >> 4, e, tile);
        return;
    }
    if (id == 9216) {                          // hdr zero
        hdr[threadIdx.x] = 0;
        return;
    }
    // ---- gate: 4 tokens per block ----
    const int tid = threadIdx.x, lane = tid & 63, wv = tid >> 6;
    const int n = (id - 8192) * 4 + wv;
    float a[NE] = {0.f,0.f,0.f,0.f,0.f,0.f,0.f,0.f};
    const float* xr = x + (size_t)n * DIM;
    unsigned short* xo = xbf + (size_t)n * DIM;
    #pragma unroll
    for (int c = 0; c < 4; ++c) {
        const int d0 = c * 256 + lane * 4;
        const float4 xv = *reinterpret_cast<const float4*>(xr + d0);
        u16x4 o = { f2bf(xv.x), f2bf(xv.y), f2bf(xv.z), f2bf(xv.w) };
        *reinterpret_cast<u16x4*>(xo + d0) = o;
        const float* g = gw + (size_t)d0 * NE;
        const float xs[4] = {xv.x, xv.y, xv.z, xv.w};
        #pragma unroll
        for (int j = 0; j < 4; ++j)
            #pragma unroll
            for (int e = 0; e < NE; ++e)
                a[e] = fmaf(xs[j], g[j*NE + e], a[e]);
    }
    #pragma unroll
    for (int e = 0; e < NE; ++e)
        #pragma unroll
        for (int off = 32; off > 0; off >>= 1)
            a[e] += __shfl_xor(a[e], off);
    if (lane == 0) {
        float lg[NE], slg = 0.f, mx = -1e30f;
        #pragma unroll
        for (int e = 0; e < NE; ++e) { lg[e] = a[e] + gb[e]; slg += lg[e]; mx = fmaxf(mx, lg[e]); }
        float se = 0.f;
        #pragma unroll
        for (int e = 0; e < NE; ++e) se += expf(lg[e] - mx);
        const float lz = mx + logf(se);
        int i0 = 0;
        #pragma unroll
        for (int e = 1; e < NE; ++e) if (lg[e] > lg[i0]) i0 = e;
        int i1 = (i0 == 0) ? 1 : 0;
        #pragma unroll
        for (int e = 0; e < NE; ++e) if (e != i0 && lg[e] > lg[i1]) i1 = e;
        const float ex = expf(lg[i1] - lg[i0]);
        const float p0 = 1.f / (1.f + ex);
        scores[2*n]   = p0;
        scores[2*n+1] = ex * p0;
        eidx[2*n]   = i0;
        eidx[2*n+1] = i1;
        auxp[n] = slg - 8.f * lz;           // sum_e logp_e for this token (no atomics)
    }
}

// Single block: histogram of 8192 expert indices + 128-padded offsets. No global atomics.
__global__ __launch_bounds__(1024) void hist_offsets_kernel(const int* __restrict__ eidx, int* __restrict__ hdr)
{
    __shared__ int cnt[NE];
    const int tid = threadIdx.x, lane = tid & 63;
    if (tid < NE) cnt[tid] = 0;
    __syncthreads();
    int local[NE] = {0,0,0,0,0,0,0,0};
    #pragma unroll
    for (int j = 0; j < 8; ++j) {
        const int e = eidx[j * 1024 + tid];
        #pragma unroll
        for (int k = 0; k < NE; ++k) local[k] += (e == k);
    }
    #pragma unroll
    for (int k = 0; k < NE; ++k)
        #pragma unroll
        for (int off = 32; off > 0; off >>= 1)
            local[k] += __shfl_xor(local[k], off);
    if (lane == 0)
        #pragma unroll
        for (int k = 0; k < NE; ++k) atomicAdd(&cnt[k], local[k]);   // LDS atomics
    __syncthreads();
    if (tid == 0) {
        int off = 0;
        for (int e = 0; e < NE; ++e) {
            hdr[16 + e] = off;
            off += (cnt[e] + BM - 1) & ~(BM - 1);
        }
        hdr[16 + NE] = off;   // padded_total
    }
}

// Block-aggregated slot assignment + slot->token inverse map.
__global__ __launch_bounds__(256) void assign_kernel(
    const int* __restrict__ eidx, int* __restrict__ hdr, int* __restrict__ slot_of,
    int* __restrict__ s2t)
{
    __shared__ int cnt[NE];
    __shared__ int base[NE];
    const int tid = threadIdx.x;
    const int p = blockIdx.x * 256 + tid;
    if (tid < NE) cnt[tid] = 0;
    __syncthreads();
    const int e = eidx[p];
    const int pos = atomicAdd(&cnt[e], 1);          // LDS atomic
    __syncthreads();
    if (tid < NE) base[tid] = atomicAdd(&hdr[32 + 16 * tid], cnt[tid]);  // own cacheline
    __syncthreads();
    const int slot = hdr[16 + e] + base[e] + pos;
    slot_of[p] = slot;
    s2t[slot] = p >> 1;                             // token of this slot (pad slots: stale, clamped in gemm)
}

// C[row][n] = (GELU? gelu : id)(A[row][:] @ B_e[:][n]);  A:[*][KD] bf16, Bt:[E][ND][KD] bf16
// R6-proven: 128x128 tile, 4 waves, BK=32, 3-deep LDS pipeline (48 KB),
// counted vmcnt(8/4/0), XOR bank swizzle (measured zero-conflict), slot->token gather on A.
template<int KD, int ND, bool GELU, bool GATHER>
__global__ __launch_bounds__(256, 2) void gemm_kernel(
    const unsigned short* __restrict__ A, const unsigned short* __restrict__ Bt,
    unsigned short* __restrict__ Cout, const int* __restrict__ hdr, const int* __restrict__ s2t)
{
    const int tid = threadIdx.x, lane = tid & 63, wv = tid >> 6;
    const int wr = wv >> 1, wc = wv & 1;
    const int row0 = blockIdx.y * BM;
    if (row0 >= hdr[16 + NE]) return;          // beyond padded_total (uniform)
    int e = 0;
    while (e < NE - 1 && hdr[16 + e + 1] <= row0) ++e;
    const unsigned short* Be = Bt + (size_t)e * KD * ND + (size_t)(blockIdx.x * 128) * KD;

    // 3 buffers x (A 4096 shorts | B 4096 shorts) = 48 KB
    __shared__ __align__(16) unsigned short lds[3 * 8192];

    f32x4 acc[4][4] = {};
    const int srow = lane >> 2;
    const int scolX = (((lane & 3) ^ ((lane >> 3) & 3)) * 8);   // swizzled source col (elements)
    const int ch0 = wv * 2, ch1 = ch0 + 1;                      // wave-uniform chunk ids

    // per-thread global A rows (resolved once; GATHER indirects slot->token, clamped)
    int ta0 = row0 + ch0 * 16 + srow, ta1 = row0 + ch1 * 16 + srow;
    if (GATHER) {
        int t0 = s2t[ta0]; if ((unsigned)t0 >= NTOK) t0 = 0; ta0 = t0;   // pad slots: any valid row
        int t1 = s2t[ta1]; if ((unsigned)t1 >= NTOK) t1 = 0; ta1 = t1;
    }
    const size_t ga0 = (size_t)ta0 * KD, ga1 = (size_t)ta1 * KD;
    const size_t gb0 = (size_t)(ch0 * 16 + srow) * KD;
    const size_t gb1 = (size_t)(ch1 * 16 + srow) * KD;

    auto STAGE = [&](unsigned off, int k0) {   // off in shorts
        load_lds16(A  + ga0 + k0 + scolX, &lds[off + ch0 * 512]);
        load_lds16(A  + ga1 + k0 + scolX, &lds[off + ch1 * 512]);
        load_lds16(Be + gb0 + k0 + scolX, &lds[off + 4096 + ch0 * 512]);
        load_lds16(Be + gb1 + k0 + scolX, &lds[off + 4096 + ch1 * 512]);
    };

    const int r = lane & 15;
    const int hsegX = (((lane >> 4) ^ ((r >> 1) & 3)) * 8);     // swizzled frag col (shorts)

    unsigned o0 = 0, o1 = 8192, o2 = 16384;
    STAGE(o0, 0);
    STAGE(o1, 32);
    const int NT = KD / 32;
    for (int t = 0; t < NT; ++t) {
        if (t + 2 < NT) {
            STAGE(o2, (t + 2) * 32);                              // prefetch 2 ahead
            asm volatile("s_waitcnt vmcnt(8)" ::: "memory");      // tile t landed
        } else if (t + 1 < NT) {
            asm volatile("s_waitcnt vmcnt(4)" ::: "memory");
        } else {
            asm volatile("s_waitcnt vmcnt(0)" ::: "memory");
        }
        __builtin_amdgcn_s_barrier();          // all waves' tile-t loads landed
        __builtin_amdgcn_sched_barrier(0);
        short8 af[4], bfr[4];
        #pragma unroll
        for (int mm = 0; mm < 4; ++mm)
            af[mm] = *reinterpret_cast<const short8*>(&lds[o0 + (wr*64 + mm*16 + r) * 32 + hsegX]);
        #pragma unroll
        for (int nn = 0; nn < 4; ++nn)
            bfr[nn] = *reinterpret_cast<const short8*>(&lds[o0 + 4096 + (wc*64 + nn*16 + r) * 32 + hsegX]);
        __builtin_amdgcn_s_setprio(1);
        #pragma unroll
        for (int mm = 0; mm < 4; ++mm)
            #pragma unroll
            for (int nn = 0; nn < 4; ++nn)
                acc[mm][nn] = __builtin_amdgcn_mfma_f32_16x16x32_bf16(af[mm], bfr[nn], acc[mm][nn], 0, 0, 0);
        __builtin_amdgcn_s_setprio(0);
        __builtin_amdgcn_sched_barrier(0);
        __builtin_amdgcn_s_barrier();          // reads of o0 done -> next STAGE may overwrite
        const unsigned tmp = o0; o0 = o1; o1 = o2; o2 = tmp;
    }

    const int col = lane & 15, rb = (lane >> 4) * 4;      // C/D: col=lane&15, row=(lane>>4)*4+j
    #pragma unroll
    for (int mm = 0; mm < 4; ++mm)
        #pragma unroll
        for (int nn = 0; nn < 4; ++nn)
            #pragma unroll
            for (int j = 0; j < 4; ++j) {
                const int grow = row0 + wr*64 + mm*16 + rb + j;
                const int gcol = blockIdx.x * 128 + wc*64 + nn*16 + col;
                float v = acc[mm][nn][j];
                if (GELU) v = 0.5f * v * (1.0f + erff(v * 0.70710678118654752f));
                Cout[(size_t)grow * ND + gcol] = f2bf(v);
            }
}

// combine (blocks 0..NTOK-1) + aux reduction (block NTOK)
__global__ __launch_bounds__(256) void combine_aux_kernel(
    const unsigned short* __restrict__ sout, const float* __restrict__ scores,
    const int* __restrict__ slot_of, const float* __restrict__ auxp, float* __restrict__ out)
{
    const int n = blockIdx.x;
    const int tid = threadIdx.x;
    if (n == NTOK) {                           // aux loss
        __shared__ float red[4];
        const int lane = tid & 63, wv = tid >> 6;
        float s = 0.f;
        for (int i = tid; i < NTOK; i += 256) s += auxp[i];
        #pragma unroll
        for (int off = 32; off > 0; off >>= 1) s += __shfl_xor(s, off);
        if (lane == 0) red[wv] = s;
        __syncthreads();
        if (tid == 0) {
            const float tot = red[0] + red[1] + red[2] + red[3];
            const float t = 0.125f;
            out[(size_t)NTOK * DIM] = 0.01f * t * (logf(t) - tot / (float)(NTOK * NE));
        }
        return;
    }
    const float s0 = scores[2*n], s1 = scores[2*n+1];
    const int sa = slot_of[2*n], sb = slot_of[2*n+1];
    const int d = tid * 4;
    const u16x4 va = *reinterpret_cast<const u16x4*>(sout + (size_t)sa * DIM + d);
    const u16x4 vb = *reinterpret_cast<const u16x4*>(sout + (size_t)sb * DIM + d);
    float4 o;
    o.x = s0*bf2f(va.x) + s1*bf2f(vb.x);
    o.y = s0*bf2f(va.y) + s1*bf2f(vb.y);
    o.z = s0*bf2f(va.z) + s1*bf2f(vb.z);
    o.w = s0*bf2f(va.w) + s1*bf2f(vb.w);
    *reinterpret_cast<float4*>(out + (size_t)n * DIM + d) = o;
}

// ---- workspace layout (bytes) ----
constexpr size_t OFF_SCORES = 2048;
constexpr size_t OFF_IDX    = OFF_SCORES + (size_t)NTOK * 2 * 4;
constexpr size_t OFF_SLOT   = OFF_IDX    + (size_t)NTOK * 2 * 4;
constexpr size_t OFF_AUXP   = OFF_SLOT   + (size_t)NTOK * 2 * 4;
constexpr size_t OFF_S2T    = OFF_AUXP   + (size_t)NTOK * 4;
constexpr size_t OFF_XBF    = 262144;
constexpr size_t OFF_W1T    = OFF_XBF + (size_t)NTOK * DIM * 2;
constexpr size_t OFF_W2T    = OFF_W1T + (size_t)NE * DIM * HDIM * 2;
constexpr size_t OFF_H      = OFF_W2T + (size_t)NE * DIM * HDIM * 2;
constexpr size_t OFF_SOUT   = OFF_H   + (size_t)MAXROWS * HDIM * 2;
constexpr size_t WS_NEED    = OFF_SOUT + (size_t)MAXROWS * DIM * 2;

extern "C" void kernel_launch(void* const* d_in, const int* in_sizes, int n_in,
                              void* d_out, int out_size, void* d_ws, size_t ws_size,
                              hipStream_t stream) {
    const float* x  = (const float*)d_in[0];
    const float* gw = (const float*)d_in[1];
    const float* gb = (const float*)d_in[2];
    const float* w1 = (const float*)d_in[3];
    const float* w2 = (const float*)d_in[4];
    float* out = (float*)d_out;

    if (ws_size < WS_NEED) return;   // fail loudly (output stays poisoned)

    char* ws = (char*)d_ws;
    int*   hdr     = (int*)ws;
    float* scores  = (float*)(ws + OFF_SCORES);
    int*   eidx    = (int*)(ws + OFF_IDX);
    int*   slot_of = (int*)(ws + OFF_SLOT);
    float* auxp    = (float*)(ws + OFF_AUXP);
    int*   s2t     = (int*)(ws + OFF_S2T);
    unsigned short* xbf = (unsigned short*)(ws + OFF_XBF);
    unsigned short* w1t = (unsigned short*)(ws + OFF_W1T);
    unsigned short* w2t = (unsigned short*)(ws + OFF_W2T);
    unsigned short* h   = (unsigned short*)(ws + OFF_H);
    unsigned short* sout= (unsigned short*)(ws + OFF_SOUT);

    prep_kernel<<<9217, 256, 0, stream>>>(x, gw, gb, w1, w2, w1t, w2t,
                                          scores, eidx, auxp, xbf, hdr);
    hist_offsets_kernel<<<1, 1024, 0, stream>>>(eidx, hdr);
    assign_kernel<<<2*NTOK/256, 256, 0, stream>>>(eidx, hdr, slot_of, s2t);
    gemm_kernel<DIM, HDIM, true,  true ><<<dim3(HDIM/128, MBLK), 256, 0, stream>>>(xbf, w1t, h, hdr, s2t);
    gemm_kernel<HDIM, DIM, false, false><<<dim3(DIM/128, MBLK), 256, 0, stream>>>(h, w2t, sout, hdr, s2t);
    combine_aux_kernel<<<NTOK + 1, 256, 0, stream>>>(sout, scores, slot_of, auxp, out);
}

// Round 12
// 197.166 us; speedup vs baseline: 1.1460x; 1.0081x over previous
//
#include <hip/hip_runtime.h>
#include <cstdint>
#include <cstddef>

#define NTOK 4096           // B*S
#define DIM  1024           // D
#define HDIM 2048           // H
#define NE   8              // experts
#define BM   128            // GEMM row tile / expert padding
#define MAXROWS (2*NTOK + NE*BM)   // 9216 worst-case padded slots
#define MBLK (MAXROWS/BM)          // 72 m-blocks (fixed grid)

typedef __attribute__((ext_vector_type(8))) short short8;
typedef __attribute__((ext_vector_type(4))) float f32x4;
typedef __attribute__((ext_vector_type(4))) unsigned short u16x4;
typedef __attribute__((ext_vector_type(8))) unsigned short u16x8;

__device__ __forceinline__ unsigned short f2bf(float f) {
    union { float f; unsigned int u; } v; v.f = f;
    return (unsigned short)((v.u + 0x7FFFu + ((v.u >> 16) & 1u)) >> 16);
}
__device__ __forceinline__ float bf2f(unsigned short u) {
    union { unsigned int u; float f; } v; v.u = ((unsigned int)u) << 16;
    return v.f;
}

__device__ __forceinline__ void load_lds16(const void* g, void* l) {
    __builtin_amdgcn_global_load_lds(
        (const __attribute__((address_space(1))) void*)(uintptr_t)g,
        (__attribute__((address_space(3))) void*)(uintptr_t)l, 16, 0, 0);
}

// hdr layout (ints): [16..24] padded offsets (off[8]=padded_total), [32 + 16*e] cursors
// Merged: zero hdr (block 0) + gw [1024][8] f32 -> gwt [8][1024] f32
__global__ __launch_bounds__(256) void init_gwt_kernel(const float* __restrict__ gw,
                                                       float* __restrict__ gwt, int* __restrict__ hdr) {
    if (blockIdx.x == 0) hdr[threadIdx.x] = 0;
    const int i = blockIdx.x * 256 + threadIdx.x;   // 8192 total
    const int d = i >> 3, e = i & 7;
    gwt[e * DIM + d] = gw[i];
}

// Atomic-free gate (coalesced gwt): writes scores, eidx, aux partial, token-major bf16 x.
__global__ __launch_bounds__(256) void gate_kernel(
    const float* __restrict__ x, const float* __restrict__ gwt, const float* __restrict__ gb,
    float* __restrict__ scores, int* __restrict__ eidx, float* __restrict__ auxp,
    unsigned short* __restrict__ xbf)
{
    const int tid = threadIdx.x, lane = tid & 63, wv = tid >> 6;
    const int n = blockIdx.x * 4 + wv;
    float a[NE] = {0.f,0.f,0.f,0.f,0.f,0.f,0.f,0.f};
    const float* xr = x + (size_t)n * DIM;
    unsigned short* xo = xbf + (size_t)n * DIM;
    #pragma unroll
    for (int c = 0; c < 4; ++c) {
        const int d0 = c * 256 + lane * 4;
        const float4 xv = *reinterpret_cast<const float4*>(xr + d0);
        u16x4 o = { f2bf(xv.x), f2bf(xv.y), f2bf(xv.z), f2bf(xv.w) };
        *reinterpret_cast<u16x4*>(xo + d0) = o;
        #pragma unroll
        for (int e = 0; e < NE; ++e) {
            const float4 gv = *reinterpret_cast<const float4*>(gwt + e * DIM + d0);  // coalesced
            a[e] = fmaf(xv.x, gv.x, a[e]);
            a[e] = fmaf(xv.y, gv.y, a[e]);
            a[e] = fmaf(xv.z, gv.z, a[e]);
            a[e] = fmaf(xv.w, gv.w, a[e]);
        }
    }
    #pragma unroll
    for (int e = 0; e < NE; ++e)
        #pragma unroll
        for (int off = 32; off > 0; off >>= 1)
            a[e] += __shfl_xor(a[e], off);
    if (lane == 0) {
        float lg[NE], slg = 0.f, mx = -1e30f;
        #pragma unroll
        for (int e = 0; e < NE; ++e) { lg[e] = a[e] + gb[e]; slg += lg[e]; mx = fmaxf(mx, lg[e]); }
        float se = 0.f;
        #pragma unroll
        for (int e = 0; e < NE; ++e) se += expf(lg[e] - mx);
        const float lz = mx + logf(se);
        int i0 = 0;
        #pragma unroll
        for (int e = 1; e < NE; ++e) if (lg[e] > lg[i0]) i0 = e;
        int i1 = (i0 == 0) ? 1 : 0;
        #pragma unroll
        for (int e = 0; e < NE; ++e) if (e != i0 && lg[e] > lg[i1]) i1 = e;
        const float ex = expf(lg[i1] - lg[i0]);
        const float p0 = 1.f / (1.f + ex);
        scores[2*n]   = p0;
        scores[2*n+1] = ex * p0;
        eidx[2*n]   = i0;
        eidx[2*n+1] = i1;
        auxp[n] = slg - 8.f * lz;           // sum_e logp_e for this token (no atomics)
    }
}

// Single block: histogram of 8192 expert indices + 128-padded offsets. No global atomics.
__global__ __launch_bounds__(1024) void hist_offsets_kernel(const int* __restrict__ eidx, int* __restrict__ hdr)
{
    __shared__ int cnt[NE];
    const int tid = threadIdx.x, lane = tid & 63;
    if (tid < NE) cnt[tid] = 0;
    __syncthreads();
    int local[NE] = {0,0,0,0,0,0,0,0};
    #pragma unroll
    for (int j = 0; j < 8; ++j) {
        const int e = eidx[j * 1024 + tid];
        #pragma unroll
        for (int k = 0; k < NE; ++k) local[k] += (e == k);
    }
    #pragma unroll
    for (int k = 0; k < NE; ++k)
        #pragma unroll
        for (int off = 32; off > 0; off >>= 1)
            local[k] += __shfl_xor(local[k], off);
    if (lane == 0)
        #pragma unroll
        for (int k = 0; k < NE; ++k) atomicAdd(&cnt[k], local[k]);   // LDS atomics
    __syncthreads();
    if (tid == 0) {
        int off = 0;
        for (int e = 0; e < NE; ++e) {
            hdr[16 + e] = off;
            off += (cnt[e] + BM - 1) & ~(BM - 1);
        }
        hdr[16 + NE] = off;   // padded_total
    }
}

// Block-aggregated slot assignment + slot->token inverse map.
__global__ __launch_bounds__(256) void assign_kernel(
    const int* __restrict__ eidx, int* __restrict__ hdr, int* __restrict__ slot_of,
    int* __restrict__ s2t)
{
    __shared__ int cnt[NE];
    __shared__ int base[NE];
    const int tid = threadIdx.x;
    const int p = blockIdx.x * 256 + tid;
    if (tid < NE) cnt[tid] = 0;
    __syncthreads();
    const int e = eidx[p];
    const int pos = atomicAdd(&cnt[e], 1);          // LDS atomic
    __syncthreads();
    if (tid < NE) base[tid] = atomicAdd(&hdr[32 + 16 * tid], cnt[tid]);  // own cacheline
    __syncthreads();
    const int slot = hdr[16 + e] + base[e] + pos;
    slot_of[p] = slot;
    s2t[slot] = p >> 1;                             // token of this slot (pad slots: stale, clamped in gemm)
}

// in: [E][R][C] f32  ->  out: [E][C][R] bf16, 64x64 tiles, coalesced u16x8 stores.
__global__ __launch_bounds__(256) void transpose_kernel(
    const float* __restrict__ in, unsigned short* __restrict__ out, int R, int C)
{
    __shared__ unsigned short tile[64][72];   // [c][r], pad 8 shorts
    const int e = blockIdx.z;
    in  += (size_t)e * R * C;
    out += (size_t)e * R * C;
    const int c0 = blockIdx.x * 64, r0 = blockIdx.y * 64;
    const int t = threadIdx.x;
    const int lc = (t & 15) * 4, lr = t >> 4;
    #pragma unroll
    for (int p = 0; p < 4; ++p) {
        const int r = lr + p * 16;
        const float4 v = *reinterpret_cast<const float4*>(in + (size_t)(r0 + r) * C + c0 + lc);
        tile[lc+0][r] = f2bf(v.x);
        tile[lc+1][r] = f2bf(v.y);
        tile[lc+2][r] = f2bf(v.z);
        tile[lc+3][r] = f2bf(v.w);
    }
    __syncthreads();
    const int oc = t >> 2, os = (t & 3) * 16;
    const u16x8 a = *reinterpret_cast<const u16x8*>(&tile[oc][os]);
    const u16x8 b = *reinterpret_cast<const u16x8*>(&tile[oc][os + 8]);
    unsigned short* orow = out + (size_t)(c0 + oc) * R + r0 + os;
    *reinterpret_cast<u16x8*>(orow)     = a;
    *reinterpret_cast<u16x8*>(orow + 8) = b;
}

// C[row][n] = (GELU? gelu : id)(A[row][:] @ B_e[:][n]);  A:[*][KD] bf16, Bt:[E][ND][KD] bf16
// R6-proven: 128x128 tile, 4 waves, BK=32, 3-deep LDS pipeline (48 KB),
// counted vmcnt(8/4/0), XOR bank swizzle (measured zero-conflict), slot->token gather on A.
template<int KD, int ND, bool GELU, bool GATHER>
__global__ __launch_bounds__(256, 2) void gemm_kernel(
    const unsigned short* __restrict__ A, const unsigned short* __restrict__ Bt,
    unsigned short* __restrict__ Cout, const int* __restrict__ hdr, const int* __restrict__ s2t)
{
    const int tid = threadIdx.x, lane = tid & 63, wv = tid >> 6;
    const int wr = wv >> 1, wc = wv & 1;
    const int row0 = blockIdx.y * BM;
    if (row0 >= hdr[16 + NE]) return;          // beyond padded_total (uniform)
    int e = 0;
    while (e < NE - 1 && hdr[16 + e + 1] <= row0) ++e;
    const unsigned short* Be = Bt + (size_t)e * KD * ND + (size_t)(blockIdx.x * 128) * KD;

    // 3 buffers x (A 4096 shorts | B 4096 shorts) = 48 KB
    __shared__ __align__(16) unsigned short lds[3 * 8192];

    f32x4 acc[4][4] = {};
    const int srow = lane >> 2;
    const int scolX = (((lane & 3) ^ ((lane >> 3) & 3)) * 8);   // swizzled source col (elements)
    const int ch0 = wv * 2, ch1 = ch0 + 1;                      // wave-uniform chunk ids

    // per-thread global A rows (resolved once; GATHER indirects slot->token, clamped)
    int ta0 = row0 + ch0 * 16 + srow, ta1 = row0 + ch1 * 16 + srow;
    if (GATHER) {
        int t0 = s2t[ta0]; if ((unsigned)t0 >= NTOK) t0 = 0; ta0 = t0;   // pad slots: any valid row
        int t1 = s2t[ta1]; if ((unsigned)t1 >= NTOK) t1 = 0; ta1 = t1;
    }
    const size_t ga0 = (size_t)ta0 * KD, ga1 = (size_t)ta1 * KD;
    const size_t gb0 = (size_t)(ch0 * 16 + srow) * KD;
    const size_t gb1 = (size_t)(ch1 * 16 + srow) * KD;

    auto STAGE = [&](unsigned off, int k0) {   // off in shorts
        load_lds16(A  + ga0 + k0 + scolX, &lds[off + ch0 * 512]);
        load_lds16(A  + ga1 + k0 + scolX, &lds[off + ch1 * 512]);
        load_lds16(Be + gb0 + k0 + scolX, &lds[off + 4096 + ch0 * 512]);
        load_lds16(Be + gb1 + k0 + scolX, &lds[off + 4096 + ch1 * 512]);
    };

    const int r = lane & 15;
    const int hsegX = (((lane >> 4) ^ ((r >> 1) & 3)) * 8);     // swizzled frag col (shorts)

    unsigned o0 = 0, o1 = 8192, o2 = 16384;
    STAGE(o0, 0);
    STAGE(o1, 32);
    const int NT = KD / 32;
    for (int t = 0; t < NT; ++t) {
        if (t + 2 < NT) {
            STAGE(o2, (t + 2) * 32);                              // prefetch 2 ahead
            asm volatile("s_waitcnt vmcnt(8)" ::: "memory");      // tile t landed
        } else if (t + 1 < NT) {
            asm volatile("s_waitcnt vmcnt(4)" ::: "memory");
        } else {
            asm volatile("s_waitcnt vmcnt(0)" ::: "memory");
        }
        __builtin_amdgcn_s_barrier();          // all waves' tile-t loads landed
        __builtin_amdgcn_sched_barrier(0);
        short8 af[4], bfr[4];
        #pragma unroll
        for (int mm = 0; mm < 4; ++mm)
            af[mm] = *reinterpret_cast<const short8*>(&lds[o0 + (wr*64 + mm*16 + r) * 32 + hsegX]);
        #pragma unroll
        for (int nn = 0; nn < 4; ++nn)
            bfr[nn] = *reinterpret_cast<const short8*>(&lds[o0 + 4096 + (wc*64 + nn*16 + r) * 32 + hsegX]);
        __builtin_amdgcn_s_setprio(1);
        #pragma unroll
        for (int mm = 0; mm < 4; ++mm)
            #pragma unroll
            for (int nn = 0; nn < 4; ++nn)
                acc[mm][nn] = __builtin_amdgcn_mfma_f32_16x16x32_bf16(af[mm], bfr[nn], acc[mm][nn], 0, 0, 0);
        __builtin_amdgcn_s_setprio(0);
        __builtin_amdgcn_sched_barrier(0);
        __builtin_amdgcn_s_barrier();          // reads of o0 done -> next STAGE may overwrite
        const unsigned tmp = o0; o0 = o1; o1 = o2; o2 = tmp;
    }

    const int col = lane & 15, rb = (lane >> 4) * 4;      // C/D: col=lane&15, row=(lane>>4)*4+j
    #pragma unroll
    for (int mm = 0; mm < 4; ++mm)
        #pragma unroll
        for (int nn = 0; nn < 4; ++nn)
            #pragma unroll
            for (int j = 0; j < 4; ++j) {
                const int grow = row0 + wr*64 + mm*16 + rb + j;
                const int gcol = blockIdx.x * 128 + wc*64 + nn*16 + col;
                float v = acc[mm][nn][j];
                if (GELU) v = 0.5f * v * (1.0f + erff(v * 0.70710678118654752f));
                Cout[(size_t)grow * ND + gcol] = f2bf(v);
            }
}

// combine (blocks 0..NTOK-1) + aux reduction (block NTOK)
__global__ __launch_bounds__(256) void combine_aux_kernel(
    const unsigned short* __restrict__ sout, const float* __restrict__ scores,
    const int* __restrict__ slot_of, const float* __restrict__ auxp, float* __restrict__ out)
{
    const int n = blockIdx.x;
    const int tid = threadIdx.x;
    if (n == NTOK) {                           // aux loss
        __shared__ float red[4];
        const int lane = tid & 63, wv = tid >> 6;
        float s = 0.f;
        for (int i = tid; i < NTOK; i += 256) s += auxp[i];
        #pragma unroll
        for (int off = 32; off > 0; off >>= 1) s += __shfl_xor(s, off);
        if (lane == 0) red[wv] = s;
        __syncthreads();
        if (tid == 0) {
            const float tot = red[0] + red[1] + red[2] + red[3];
            const float t = 0.125f;
            out[(size_t)NTOK * DIM] = 0.01f * t * (logf(t) - tot / (float)(NTOK * NE));
        }
        return;
    }
    const float s0 = scores[2*n], s1 = scores[2*n+1];
    const int sa = slot_of[2*n], sb = slot_of[2*n+1];
    const int d = tid * 4;
    const u16x4 va = *reinterpret_cast<const u16x4*>(sout + (size_t)sa * DIM + d);
    const u16x4 vb = *reinterpret_cast<const u16x4*>(sout + (size_t)sb * DIM + d);
    float4 o;
    o.x = s0*bf2f(va.x) + s1*bf2f(vb.x);
    o.y = s0*bf2f(va.y) + s1*bf2f(vb.y);
    o.z = s0*bf2f(va.z) + s1*bf2f(vb.z);
    o.w = s0*bf2f(va.w) + s1*bf2f(vb.w);
    *reinterpret_cast<float4*>(out + (size_t)n * DIM + d) = o;
}

// ---- workspace layout (bytes) ----
constexpr size_t OFF_SCORES = 2048;
constexpr size_t OFF_IDX    = OFF_SCORES + (size_t)NTOK * 2 * 4;
constexpr size_t OFF_SLOT   = OFF_IDX    + (size_t)NTOK * 2 * 4;
constexpr size_t OFF_AUXP   = OFF_SLOT   + (size_t)NTOK * 2 * 4;
constexpr size_t OFF_S2T    = OFF_AUXP   + (size_t)NTOK * 4;
constexpr size_t OFF_GWT    = OFF_S2T    + (size_t)MAXROWS * 4;
constexpr size_t OFF_XBF    = 262144;
constexpr size_t OFF_W1T    = OFF_XBF + (size_t)NTOK * DIM * 2;
constexpr size_t OFF_W2T    = OFF_W1T + (size_t)NE * DIM * HDIM * 2;
constexpr size_t OFF_H      = OFF_W2T + (size_t)NE * DIM * HDIM * 2;
constexpr size_t OFF_SOUT   = OFF_H   + (size_t)MAXROWS * HDIM * 2;
constexpr size_t WS_NEED    = OFF_SOUT + (size_t)MAXROWS * DIM * 2;

extern "C" void kernel_launch(void* const* d_in, const int* in_sizes, int n_in,
                              void* d_out, int out_size, void* d_ws, size_t ws_size,
                              hipStream_t stream) {
    const float* x  = (const float*)d_in[0];
    const float* gw = (const float*)d_in[1];
    const float* gb = (const float*)d_in[2];
    const float* w1 = (const float*)d_in[3];
    const float* w2 = (const float*)d_in[4];
    float* out = (float*)d_out;

    if (ws_size < WS_NEED) return;   // fail loudly (output stays poisoned)

    char* ws = (char*)d_ws;
    int*   hdr     = (int*)ws;
    float* scores  = (float*)(ws + OFF_SCORES);
    int*   eidx    = (int*)(ws + OFF_IDX);
    int*   slot_of = (int*)(ws + OFF_SLOT);
    float* auxp    = (float*)(ws + OFF_AUXP);
    int*   s2t     = (int*)(ws + OFF_S2T);
    float* gwt     = (float*)(ws + OFF_GWT);
    unsigned short* xbf = (unsigned short*)(ws + OFF_XBF);
    unsigned short* w1t = (unsigned short*)(ws + OFF_W1T);
    unsigned short* w2t = (unsigned short*)(ws + OFF_W2T);
    unsigned short* h   = (unsigned short*)(ws + OFF_H);
    unsigned short* sout= (unsigned short*)(ws + OFF_SOUT);

    init_gwt_kernel<<<DIM*NE/256, 256, 0, stream>>>(gw, gwt, hdr);
    transpose_kernel<<<dim3(HDIM/64, DIM/64, NE), 256, 0, stream>>>(w1, w1t, DIM, HDIM);
    transpose_kernel<<<dim3(DIM/64, HDIM/64, NE), 256, 0, stream>>>(w2, w2t, HDIM, DIM);
    gate_kernel<<<NTOK/4, 256, 0, stream>>>(x, gwt, gb, scores, eidx, auxp, xbf);
    hist_offsets_kernel<<<1, 1024, 0, stream>>>(eidx, hdr);
    assign_kernel<<<2*NTOK/256, 256, 0, stream>>>(eidx, hdr, slot_of, s2t);
    gemm_kernel<DIM, HDIM, true,  true ><<<dim3(HDIM/128, MBLK), 256, 0, stream>>>(xbf, w1t, h, hdr, s2t);
    gemm_kernel<HDIM, DIM, false, false><<<dim3(DIM/128, MBLK), 256, 0, stream>>>(h, w2t, sout, hdr, s2t);
    combine_aux_kernel<<<NTOK + 1, 256, 0, stream>>>(sout, scores, slot_of, auxp, out);
}